// Round 13
// baseline (127.491 us; speedup 1.0000x reference)
//
#include <hip/hip_runtime.h>

// B=4, S=1024, E=1024, H=16, D=64.
// qk   : [4096][2048] bf16  (Q|K), Q pre-scaled by 0.125*log2(e)
// vt   : [64 bh][64 d][1024 t] bf16  (V transposed, built in GEMM epilogue)
// ml   : invl/16 (float) per (b,h,row) -- softmax shift 0 (no max tracking)
// cmean: [4][1024] fp32 = mean_s(ctx);  context_vector = cmean @ Wout^T + bias
// GEMM uses 32x32x16 MFMA (4 waves x 64x64/wave): LDS reads 64KB/step vs 96KB
// with the 16x16 path -- kernel was LDS-read-throughput-bound.

typedef unsigned short u16;
using s16x8  = __attribute__((ext_vector_type(8)))  short;   // 8 bf16 = 4 VGPR
using f32x4  = __attribute__((ext_vector_type(4)))  float;
using f32x16 = __attribute__((ext_vector_type(16))) float;   // 32x32 MFMA C/D
using u16x4  = __attribute__((ext_vector_type(4)))  unsigned short;

#define AS1 __attribute__((address_space(1)))
#define AS3 __attribute__((address_space(3)))

#define QSCALE 0.1803368801111204f   // 0.125 * log2(e)

__device__ __forceinline__ u16 f2bf(float f) {
    unsigned u = __float_as_uint(f);
    u += 0x7fffu + ((u >> 16) & 1u);   // RTN-even
    return (u16)(u >> 16);
}

// ---------------- fused fp32->bf16 converts + cmean zero ----------------
__global__ void k_prep(const float* __restrict__ X, const float* __restrict__ W1,
                       u16* __restrict__ Xb, u16* __restrict__ W1b,
                       float* __restrict__ cmean) {
    int i = blockIdx.x * blockDim.x + threadIdx.x;
    const float* src; u16* dst; int off;
    if (i < 1048576)       { src = X;  dst = Xb;  off = i; }
    else                   { src = W1; dst = W1b; off = i - 1048576; }
    float4 v = reinterpret_cast<const float4*>(src)[off];
    u16x4 o = { f2bf(v.x), f2bf(v.y), f2bf(v.z), f2bf(v.w) };
    reinterpret_cast<u16x4*>(dst)[off] = o;
    if (i < 4096) cmean[i] = 0.f;
}

// ---------------- 128x128 BT GEMM (QKV): 4 waves x 64x64, 32x32x16 MFMA ----------------
// T2 XOR-swizzle (rule #21 both-sides), XCD swizzle, LDS dbuf.
// A/B frag: row = lane&31, k-chunk = ks*2 + (lane>>5).  C/D: col = lane&31,
// row = (reg&3) + 8*(reg>>2) + 4*(lane>>5)   [m74/m101 verified mapping]
__global__ __launch_bounds__(256) void k_gemm_bt(
    const u16* __restrict__ A, const u16* __restrict__ B,
    const float* __restrict__ bias, u16* __restrict__ C,
    u16* __restrict__ vt) {
    const int K = 1024;
    const int nbx = gridDim.x;
    const int nwg = nbx * gridDim.y;
    const int bid = blockIdx.y * nbx + blockIdx.x;
    const int per = nwg >> 3;
    const int swz = (bid & 7) * per + (bid >> 3);
    const int n0 = (swz % nbx) * 128, m0 = (swz / nbx) * 128;
    const int tid = threadIdx.x, lane = tid & 63, w = tid >> 6;  // 4 waves
    const int wm = w >> 1, wn = w & 1;                           // 2x2 of 64x64
    const int l31 = lane & 31, g2 = lane >> 5;
    __shared__ __attribute__((aligned(16))) u16 As[2][128 * 64];
    __shared__ __attribute__((aligned(16))) u16 Bs[2][128 * 64];

    f32x16 acc[2][2];
    #pragma unroll
    for (int mi = 0; mi < 2; ++mi)
        #pragma unroll
        for (int ni = 0; ni < 2; ++ni)
            #pragma unroll
            for (int r = 0; r < 16; ++r) acc[mi][ni][r] = 0.f;

    auto STAGE = [&](int k0, int sb) {
        #pragma unroll
        for (int r = 0; r < 4; ++r) {          // 1024 chunks over 256 threads
            int c = tid + r * 256;
            int row = c >> 3, j = c & 7;
            int js = j ^ (row & 7);            // pre-swizzled source chunk
            __builtin_amdgcn_global_load_lds(
                (AS1 const void*)(A + (size_t)(m0 + row) * K + k0 + js * 8),
                (AS3 void*)(&As[sb][c * 8]), 16, 0, 0);
            __builtin_amdgcn_global_load_lds(
                (AS1 const void*)(B + (size_t)(n0 + row) * K + k0 + js * 8),
                (AS3 void*)(&Bs[sb][c * 8]), 16, 0, 0);
        }
    };

    STAGE(0, 0);
    int buf = 0;
    for (int k0 = 0; k0 < K; k0 += 64) {
        __syncthreads();                       // buf ready; buf^1 free
        if (k0 + 64 < K) STAGE(k0 + 64, buf ^ 1);
        #pragma unroll
        for (int ks = 0; ks < 4; ++ks) {       // K=16 sub-steps
            const int cx = ((ks * 2 + g2) ^ (l31 & 7)) * 8;   // swizzled chunk
            s16x8 av[2], bv[2];
            #pragma unroll
            for (int mi = 0; mi < 2; ++mi)
                av[mi] = *reinterpret_cast<const s16x8*>(
                    &As[buf][(wm * 64 + mi * 32 + l31) * 64 + cx]);
            #pragma unroll
            for (int ni = 0; ni < 2; ++ni)
                bv[ni] = *reinterpret_cast<const s16x8*>(
                    &Bs[buf][(wn * 64 + ni * 32 + l31) * 64 + cx]);
            #pragma unroll
            for (int mi = 0; mi < 2; ++mi)
                #pragma unroll
                for (int ni = 0; ni < 2; ++ni)
                    acc[mi][ni] = __builtin_amdgcn_mfma_f32_32x32x16_bf16(
                        av[mi], bv[ni], acc[mi][ni], 0, 0, 0);
        }
        buf ^= 1;
    }

    #pragma unroll
    for (int ni = 0; ni < 2; ++ni) {
        int n = n0 + wn * 64 + ni * 32 + l31;
        float scale = (n < 1024) ? QSCALE : 1.0f;
        float bvs = bias[n] * scale;
        if (n < 2048) {
            #pragma unroll
            for (int mi = 0; mi < 2; ++mi)
                #pragma unroll
                for (int r = 0; r < 16; ++r) {
                    int rowl = (r & 3) + 8 * (r >> 2) + 4 * g2;
                    int m = m0 + wm * 64 + mi * 32 + rowl;
                    C[(size_t)m * 2048 + n] = f2bf(acc[mi][ni][r] * scale + bvs);
                }
        } else {
            int hd = n - 2048;                       // h*64 + d
            #pragma unroll
            for (int mi = 0; mi < 2; ++mi)
                #pragma unroll
                for (int r = 0; r < 16; ++r) {
                    int rowl = (r & 3) + 8 * (r >> 2) + 4 * g2;
                    int m = m0 + wm * 64 + mi * 32 + rowl;
                    int b = m >> 10, t = m & 1023;
                    vt[((size_t)(b * 16 + (hd >> 6)) * 64 + (hd & 63)) * 1024 + t] =
                        f2bf(acc[mi][ni][r] + bvs);
                }
        }
    }
}

// ---------------- flash attention: per (b, h, 64-row q-tile) ----------------
__global__ __launch_bounds__(256, 4) void k_flash(const u16* __restrict__ qk,
                                                  const u16* __restrict__ vt,
                                                  float* __restrict__ ml,
                                                  float* __restrict__ cmean) {
    const int id = blockIdx.x + 16 * (blockIdx.y + 16 * blockIdx.z);
    const int x = id & 7, kq = id >> 3;
    const int gbh = x * 8 + (kq >> 4);
    const int qt = kq & 15;
    const int b = gbh >> 4, h = gbh & 15;
    const int q0 = qt * 64;
    const int tid = threadIdx.x, lane = tid & 63, w = tid >> 6;
    const int g = lane >> 4, l15 = lane & 15;
    __shared__ __attribute__((aligned(16))) u16 Ks[2][64 * 64];
    __shared__ __attribute__((aligned(16))) u16 Vt[2][64 * 64];
    __shared__ __attribute__((aligned(16))) u16 Ps[4][16 * 64];

    const size_t rowQ = (size_t)(b * 1024 + q0 + w * 16 + l15) * 2048 + h * 64;
    const s16x8 qa0 = *reinterpret_cast<const s16x8*>(qk + rowQ + g * 8);
    const s16x8 qa1 = *reinterpret_cast<const s16x8*>(qk + rowQ + 32 + g * 8);
    const s16x8 onesv = { (short)0x3F80, (short)0x3F80, (short)0x3F80, (short)0x3F80,
                          (short)0x3F80, (short)0x3F80, (short)0x3F80, (short)0x3F80 };

    const int cA = tid, cB = tid + 256;
    const int rowA = cA >> 3, jA = cA & 7, rowB = cB >> 3, jB = cB & 7;
    const u16* kbase0 = qk + (size_t)(b * 1024) * 2048 + 1024 + h * 64;
    const u16* vtb = vt + (size_t)(b * 16 + h) * 65536;

    __builtin_amdgcn_global_load_lds((AS1 const void*)(kbase0 + (size_t)rowA * 2048 + ((jA ^ (rowA & 7)) * 8)),
                                     (AS3 void*)(&Ks[0][cA * 8]), 16, 0, 0);
    __builtin_amdgcn_global_load_lds((AS1 const void*)(kbase0 + (size_t)rowB * 2048 + ((jB ^ (rowB & 7)) * 8)),
                                     (AS3 void*)(&Ks[0][cB * 8]), 16, 0, 0);
    __builtin_amdgcn_global_load_lds((AS1 const void*)(vtb + (size_t)rowA * 1024 + ((jA ^ (rowA & 7)) * 8)),
                                     (AS3 void*)(&Vt[0][cA * 8]), 16, 0, 0);
    __builtin_amdgcn_global_load_lds((AS1 const void*)(vtb + (size_t)rowB * 1024 + ((jB ^ (rowB & 7)) * 8)),
                                     (AS3 void*)(&Vt[0][cB * 8]), 16, 0, 0);

    f32x4 ctxa[4];
    #pragma unroll
    for (int nj = 0; nj < 4; ++nj) ctxa[nj] = (f32x4){0.f, 0.f, 0.f, 0.f};
    f32x4 lacc = (f32x4){0.f, 0.f, 0.f, 0.f};

    int buf = 0;
    for (int kt = 0; kt < 16; ++kt) {
        __syncthreads();
        if (kt < 15) {
            int t0n = (kt + 1) * 64;
            const u16* kbase = kbase0 + (size_t)t0n * 2048;
            __builtin_amdgcn_global_load_lds((AS1 const void*)(kbase + (size_t)rowA * 2048 + ((jA ^ (rowA & 7)) * 8)),
                                             (AS3 void*)(&Ks[buf ^ 1][cA * 8]), 16, 0, 0);
            __builtin_amdgcn_global_load_lds((AS1 const void*)(kbase + (size_t)rowB * 2048 + ((jB ^ (rowB & 7)) * 8)),
                                             (AS3 void*)(&Ks[buf ^ 1][cB * 8]), 16, 0, 0);
            const u16* vbase = vtb + t0n;
            __builtin_amdgcn_global_load_lds((AS1 const void*)(vbase + (size_t)rowA * 1024 + ((jA ^ (rowA & 7)) * 8)),
                                             (AS3 void*)(&Vt[buf ^ 1][cA * 8]), 16, 0, 0);
            __builtin_amdgcn_global_load_lds((AS1 const void*)(vbase + (size_t)rowB * 1024 + ((jB ^ (rowB & 7)) * 8)),
                                             (AS3 void*)(&Vt[buf ^ 1][cB * 8]), 16, 0, 0);
        }

        f32x4 sc[4];
        #pragma unroll
        for (int tj = 0; tj < 4; ++tj) sc[tj] = (f32x4){0.f, 0.f, 0.f, 0.f};
        __builtin_amdgcn_s_setprio(1);
        #pragma unroll
        for (int kk = 0; kk < 64; kk += 32) {
            s16x8 qa = kk ? qa1 : qa0;
            #pragma unroll
            for (int tj = 0; tj < 4; ++tj) {
                int trow = tj * 16 + l15;
                s16x8 kb = *reinterpret_cast<const s16x8*>(
                    &Ks[buf][trow * 64 + ((((kk >> 3) + g) ^ (trow & 7)) * 8)]);
                sc[tj] = __builtin_amdgcn_mfma_f32_16x16x32_bf16(kb, qa, sc[tj], 0, 0, 0);
            }
        }
        __builtin_amdgcn_s_setprio(0);

        #pragma unroll
        for (int tj = 0; tj < 4; ++tj)
            #pragma unroll
            for (int i = 0; i < 4; ++i)
                sc[tj][i] = exp2f(sc[tj][i]);

        #pragma unroll
        for (int tj = 0; tj < 4; ++tj) {
            unsigned pk01, pk23;
            asm("v_cvt_pk_bf16_f32 %0, %1, %2" : "=v"(pk01) : "v"(sc[tj][0]), "v"(sc[tj][1]));
            asm("v_cvt_pk_bf16_f32 %0, %1, %2" : "=v"(pk23) : "v"(sc[tj][2]), "v"(sc[tj][3]));
            uint2 pk = { pk01, pk23 };
            *reinterpret_cast<uint2*>(
                &Ps[w][l15 * 64 + (((tj * 2 + (g >> 1)) ^ (l15 & 7)) * 8) + (g & 1) * 4]) = pk;
        }

        __builtin_amdgcn_s_setprio(1);
        #pragma unroll
        for (int kk = 0; kk < 64; kk += 32) {
            s16x8 pa = *reinterpret_cast<const s16x8*>(
                &Ps[w][l15 * 64 + ((((kk >> 3) + g) ^ (l15 & 7)) * 8)]);
            lacc = __builtin_amdgcn_mfma_f32_16x16x32_bf16(pa, onesv, lacc, 0, 0, 0);
            #pragma unroll
            for (int nj = 0; nj < 4; ++nj) {
                int d = nj * 16 + l15;
                s16x8 vb = *reinterpret_cast<const s16x8*>(
                    &Vt[buf][d * 64 + ((((kk >> 3) + g) ^ (d & 7)) * 8)]);
                ctxa[nj] = __builtin_amdgcn_mfma_f32_16x16x32_bf16(pa, vb, ctxa[nj], 0, 0, 0);
            }
        }
        __builtin_amdgcn_s_setprio(0);
        buf ^= 1;
    }

    float inv_i[4];
    #pragma unroll
    for (int i = 0; i < 4; ++i) {
        inv_i[i] = 1.0f / lacc[i];
        if (l15 == 0)
            ml[(size_t)(b * 16 + h) * 1024 + q0 + w * 16 + g * 4 + i] = inv_i[i] * 0.0625f;
    }

    #pragma unroll
    for (int nj = 0; nj < 4; ++nj) {
        float s = ctxa[nj][0] * inv_i[0] + ctxa[nj][1] * inv_i[1]
                + ctxa[nj][2] * inv_i[2] + ctxa[nj][3] * inv_i[3];
        s += __shfl_xor(s, 16);
        s += __shfl_xor(s, 32);
        if (g == 0)
            atomicAdd(&cmean[b * 1024 + h * 64 + nj * 16 + l15], s * (1.0f / 1024.0f));
    }
}

// ---------------- attn_weights: mean over heads, 2 s-tiles per block ----------------
__global__ __launch_bounds__(256, 4) void k_attnw(const u16* __restrict__ qk,
                                                  const float* __restrict__ ml,
                                                  float* __restrict__ attnw) {
    const int tt = blockIdx.x, stp = blockIdx.y, b = blockIdx.z;
    const int s0a = stp * 128, t0 = tt * 64;
    const int tid = threadIdx.x, lane = tid & 63, w = tid >> 6;
    const int g = lane >> 4, l15 = lane & 15;
    __shared__ __attribute__((aligned(16))) u16 Ks[2][64 * 64];
    __shared__ float mls[16][128];

    #pragma unroll
    for (int r = 0; r < 8; ++r) {
        int idx = tid + r * 256;
        int hh = idx >> 7, row = idx & 127;
        mls[hh][row] = ml[(size_t)(b * 16 + hh) * 1024 + s0a + row];
    }

    const int cA = tid, cB = tid + 256;
    const int rowA = cA >> 3, jA = cA & 7, rowB = cB >> 3, jB = cB & 7;
    const u16* kbase = qk + (size_t)(b * 1024 + t0) * 2048 + 1024;
    const size_t rowQa = (size_t)(b * 1024 + s0a + w * 16 + l15) * 2048;
    const size_t rowQb = rowQa + (size_t)64 * 2048;

    __builtin_amdgcn_global_load_lds((AS1 const void*)(kbase + (size_t)rowA * 2048 + ((jA ^ (rowA & 7)) * 8)),
                                     (AS3 void*)(&Ks[0][cA * 8]), 16, 0, 0);
    __builtin_amdgcn_global_load_lds((AS1 const void*)(kbase + (size_t)rowB * 2048 + ((jB ^ (rowB & 7)) * 8)),
                                     (AS3 void*)(&Ks[0][cB * 8]), 16, 0, 0);
    s16x8 qcA0 = *reinterpret_cast<const s16x8*>(qk + rowQa + g * 8);
    s16x8 qcA1 = *reinterpret_cast<const s16x8*>(qk + rowQa + 32 + g * 8);
    s16x8 qcB0 = *reinterpret_cast<const s16x8*>(qk + rowQb + g * 8);
    s16x8 qcB1 = *reinterpret_cast<const s16x8*>(qk + rowQb + 32 + g * 8);

    f32x4 accA[4], accB[4];
    #pragma unroll
    for (int tj = 0; tj < 4; ++tj) {
        accA[tj] = (f32x4){0.f, 0.f, 0.f, 0.f};
        accB[tj] = (f32x4){0.f, 0.f, 0.f, 0.f};
    }

    int buf = 0;
    for (int h = 0; h < 16; ++h) {
        __syncthreads();
        s16x8 qnA0, qnA1, qnB0, qnB1;
        if (h < 15) {
            const u16* kb2 = kbase + (h + 1) * 64;
            __builtin_amdgcn_global_load_lds((AS1 const void*)(kb2 + (size_t)rowA * 2048 + ((jA ^ (rowA & 7)) * 8)),
                                             (AS3 void*)(&Ks[buf ^ 1][cA * 8]), 16, 0, 0);
            __builtin_amdgcn_global_load_lds((AS1 const void*)(kb2 + (size_t)rowB * 2048 + ((jB ^ (rowB & 7)) * 8)),
                                             (AS3 void*)(&Ks[buf ^ 1][cB * 8]), 16, 0, 0);
            qnA0 = *reinterpret_cast<const s16x8*>(qk + rowQa + (h + 1) * 64 + g * 8);
            qnA1 = *reinterpret_cast<const s16x8*>(qk + rowQa + (h + 1) * 64 + 32 + g * 8);
            qnB0 = *reinterpret_cast<const s16x8*>(qk + rowQb + (h + 1) * 64 + g * 8);
            qnB1 = *reinterpret_cast<const s16x8*>(qk + rowQb + (h + 1) * 64 + 32 + g * 8);
        }

        f32x4 scA[4], scB[4];
        #pragma unroll
        for (int tj = 0; tj < 4; ++tj) {
            scA[tj] = (f32x4){0.f, 0.f, 0.f, 0.f};
            scB[tj] = (f32x4){0.f, 0.f, 0.f, 0.f};
        }
        #pragma unroll
        for (int kk = 0; kk < 64; kk += 32) {
            s16x8 qaA = kk ? qcA1 : qcA0;
            s16x8 qaB = kk ? qcB1 : qcB0;
            #pragma unroll
            for (int tj = 0; tj < 4; ++tj) {
                int trow = tj * 16 + l15;
                s16x8 kb = *reinterpret_cast<const s16x8*>(
                    &Ks[buf][trow * 64 + ((((kk >> 3) + g) ^ (trow & 7)) * 8)]);
                scA[tj] = __builtin_amdgcn_mfma_f32_16x16x32_bf16(qaA, kb, scA[tj], 0, 0, 0);
                scB[tj] = __builtin_amdgcn_mfma_f32_16x16x32_bf16(qaB, kb, scB[tj], 0, 0, 0);
            }
        }
        #pragma unroll
        for (int i = 0; i < 4; ++i) {
            int row = w * 16 + g * 4 + i;
            float Ma = mls[h][row];
            float Mb = mls[h][64 + row];
            #pragma unroll
            for (int tj = 0; tj < 4; ++tj) {
                accA[tj][i] += exp2f(scA[tj][i]) * Ma;
                accB[tj][i] += exp2f(scB[tj][i]) * Mb;
            }
        }
        qcA0 = qnA0; qcA1 = qnA1; qcB0 = qnB0; qcB1 = qnB1;
        buf ^= 1;
    }

    #pragma unroll
    for (int i = 0; i < 4; ++i) {
        int rowa = s0a + w * 16 + g * 4 + i;
        #pragma unroll
        for (int tj = 0; tj < 4; ++tj) {
            attnw[(size_t)(b * 1024 + rowa) * 1024 + t0 + tj * 16 + l15] = accA[tj][i];
            attnw[(size_t)(b * 1024 + rowa + 64) * 1024 + t0 + tj * 16 + l15] = accB[tj][i];
        }
    }
}

// ---------------- out-proj on the mean (parallelized): 64 blk x 256 thr ----------------
__global__ __launch_bounds__(256) void k_outproj(const float* __restrict__ cmean,
                                                 const float* __restrict__ wout,
                                                 const float* __restrict__ bias,
                                                 float* __restrict__ out) {
    __shared__ float cs[4096];
    #pragma unroll
    for (int r = 0; r < 16; ++r) {
        int idx = threadIdx.x + r * 256;
        cs[idx] = cmean[idx];
    }
    __syncthreads();
    int G = blockIdx.x * 256 + threadIdx.x;   // 0..16383
    int e = G >> 4, ks = G & 15;
    const float4* wr = reinterpret_cast<const float4*>(wout) + (size_t)e * 256 + ks * 16;
    const float4* c0 = reinterpret_cast<const float4*>(&cs[0]) + ks * 16;
    const float4* c1 = reinterpret_cast<const float4*>(&cs[1024]) + ks * 16;
    const float4* c2 = reinterpret_cast<const float4*>(&cs[2048]) + ks * 16;
    const float4* c3 = reinterpret_cast<const float4*>(&cs[3072]) + ks * 16;
    float s0 = 0.f, s1 = 0.f, s2 = 0.f, s3 = 0.f;
    #pragma unroll
    for (int k = 0; k < 16; ++k) {
        float4 wv = wr[k];
        float4 a = c0[k], b = c1[k], c = c2[k], d = c3[k];
        s0 += a.x * wv.x + a.y * wv.y + a.z * wv.z + a.w * wv.w;
        s1 += b.x * wv.x + b.y * wv.y + b.z * wv.z + b.w * wv.w;
        s2 += c.x * wv.x + c.y * wv.y + c.z * wv.z + c.w * wv.w;
        s3 += d.x * wv.x + d.y * wv.y + d.z * wv.z + d.w * wv.w;
    }
    #pragma unroll
    for (int off = 1; off < 16; off <<= 1) {
        s0 += __shfl_xor(s0, off);
        s1 += __shfl_xor(s1, off);
        s2 += __shfl_xor(s2, off);
        s3 += __shfl_xor(s3, off);
    }
    if (ks == 0) {
        float bv = bias[e];
        out[e]        = s0 + bv;
        out[1024 + e] = s1 + bv;
        out[2048 + e] = s2 + bv;
        out[3072 + e] = s3 + bv;
    }
}

// ---------------- launch ----------------
extern "C" void kernel_launch(void* const* d_in, const int* in_sizes, int n_in,
                              void* d_out, int out_size, void* d_ws, size_t ws_size,
                              hipStream_t stream) {
    const float* lstm = (const float*)d_in[0];   // [4,1024,1024]
    const float* wqkv = (const float*)d_in[1];   // [3072,1024]
    const float* bqkv = (const float*)d_in[2];   // [3072]
    const float* wout = (const float*)d_in[3];   // [1024,1024]
    const float* bout = (const float*)d_in[4];   // [1024]
    float* out = (float*)d_out;                  // [4096 ctxvec | 4*1024*1024 attn]

    char* ws = (char*)d_ws;
    u16*   Xbf   = (u16*)(ws);                          // 8 MiB
    u16*   Wqkvb = (u16*)(ws + 8u  * 1024 * 1024);      // 6 MiB
    u16*   qkbuf = (u16*)(ws + 16u * 1024 * 1024);      // 16 MiB  [4096][2048]
    u16*   vtg   = (u16*)(ws + 32u * 1024 * 1024);      // 8 MiB   [64][64][1024]
    float* ml    = (float*)(ws + 40u * 1024 * 1024);    // 256 KiB (invl/16)
    float* cmean = (float*)(ws + 41u * 1024 * 1024);    // 16 KiB  [4][1024]

    k_prep<<<7168, 256, 0, stream>>>(lstm, wqkv, Xbf, Wqkvb, cmean);

    k_gemm_bt<<<dim3(24, 32), 256, 0, stream>>>(Xbf, Wqkvb, bqkv, qkbuf, vtg);
    k_flash<<<dim3(16, 16, 4), 256, 0, stream>>>(qkbuf, vtg, ml, cmean);
    k_attnw<<<dim3(16, 8, 4), 256, 0, stream>>>(qkbuf, ml, out + 4096);
    k_outproj<<<64, 256, 0, stream>>>(cmean, wout, bout, out);
}

// Round 14
// 120.795 us; speedup vs baseline: 1.0554x; 1.0554x over previous
//
#include <hip/hip_runtime.h>

// B=4, S=1024, E=1024, H=16, D=64.
// qk   : [4096][2048] bf16  (Q|K), Q pre-scaled by 0.125*log2(e)
// vt   : [64 bh][64 d][1024 t] bf16  (V transposed, built in GEMM epilogue)
// ml   : invl/16 (float) per (b,h,row) -- softmax shift 0 (no max tracking)
// cmean: [4][1024] fp32 = mean_s(ctx);  context_vector = cmean @ Wout^T + bias
// GEMM: R12-proven 8-wave 16x16x32 path (32x32 MFMA fragment reads are
// structurally 4-way bank-conflicted at 128B rows -- measured R13).

typedef unsigned short u16;
using s16x8 = __attribute__((ext_vector_type(8))) short;   // 8 bf16 = 4 VGPR
using f32x4 = __attribute__((ext_vector_type(4))) float;   // MFMA C/D
using u16x4 = __attribute__((ext_vector_type(4))) unsigned short;

#define AS1 __attribute__((address_space(1)))
#define AS3 __attribute__((address_space(3)))

#define QSCALE 0.1803368801111204f   // 0.125 * log2(e)

__device__ __forceinline__ u16 f2bf(float f) {
    unsigned u = __float_as_uint(f);
    u += 0x7fffu + ((u >> 16) & 1u);   // RTN-even
    return (u16)(u >> 16);
}

// ---------------- fused fp32->bf16 converts + cmean zero ----------------
__global__ void k_prep(const float* __restrict__ X, const float* __restrict__ W1,
                       u16* __restrict__ Xb, u16* __restrict__ W1b,
                       float* __restrict__ cmean) {
    int i = blockIdx.x * blockDim.x + threadIdx.x;
    const float* src; u16* dst; int off;
    if (i < 1048576)       { src = X;  dst = Xb;  off = i; }
    else                   { src = W1; dst = W1b; off = i - 1048576; }
    float4 v = reinterpret_cast<const float4*>(src)[off];
    u16x4 o = { f2bf(v.x), f2bf(v.y), f2bf(v.z), f2bf(v.w) };
    reinterpret_cast<u16x4*>(dst)[off] = o;
    if (i < 4096) cmean[i] = 0.f;
}

// ---------------- 128x128 BT GEMM (QKV), 8 waves: T2 swizzle + XCD swz + dbuf ----------------
__global__ __launch_bounds__(512) void k_gemm_bt(
    const u16* __restrict__ A, const u16* __restrict__ B,
    const float* __restrict__ bias, u16* __restrict__ C,
    u16* __restrict__ vt) {
    const int K = 1024;
    const int nbx = gridDim.x;
    const int nwg = nbx * gridDim.y;
    const int bid = blockIdx.y * nbx + blockIdx.x;
    const int per = nwg >> 3;
    const int swz = (bid & 7) * per + (bid >> 3);
    const int n0 = (swz % nbx) * 128, m0 = (swz / nbx) * 128;
    const int tid = threadIdx.x, lane = tid & 63, w = tid >> 6;
    const int wm = w >> 1, wn = w & 1;
    const int g = lane >> 4, l15 = lane & 15;
    __shared__ __attribute__((aligned(16))) u16 As[2][128 * 64];
    __shared__ __attribute__((aligned(16))) u16 Bs[2][128 * 64];

    f32x4 acc[2][4];
    #pragma unroll
    for (int mi = 0; mi < 2; ++mi)
        #pragma unroll
        for (int nj = 0; nj < 4; ++nj) acc[mi][nj] = (f32x4){0.f, 0.f, 0.f, 0.f};

    auto STAGE = [&](int k0, int sb) {
        #pragma unroll
        for (int r = 0; r < 2; ++r) {          // 1024 chunks over 512 threads
            int c = tid + r * 512;
            int row = c >> 3, j = c & 7;
            int js = j ^ (row & 7);            // pre-swizzled source chunk (rule #21)
            __builtin_amdgcn_global_load_lds(
                (AS1 const void*)(A + (size_t)(m0 + row) * K + k0 + js * 8),
                (AS3 void*)(&As[sb][c * 8]), 16, 0, 0);
            __builtin_amdgcn_global_load_lds(
                (AS1 const void*)(B + (size_t)(n0 + row) * K + k0 + js * 8),
                (AS3 void*)(&Bs[sb][c * 8]), 16, 0, 0);
        }
    };

    STAGE(0, 0);
    int buf = 0;
    for (int k0 = 0; k0 < K; k0 += 64) {
        __syncthreads();                       // buf ready; buf^1 free
        if (k0 + 64 < K) STAGE(k0 + 64, buf ^ 1);
        #pragma unroll
        for (int kk = 0; kk < 64; kk += 32) {
            const int cx0 = (((kk >> 3) + g) ^ (l15 & 7)) * 8;   // swizzled read chunk
            s16x8 av[2], bv[4];
            #pragma unroll
            for (int mi = 0; mi < 2; ++mi)
                av[mi] = *reinterpret_cast<const s16x8*>(
                    &As[buf][(wm * 32 + mi * 16 + l15) * 64 + cx0]);
            #pragma unroll
            for (int nj = 0; nj < 4; ++nj)
                bv[nj] = *reinterpret_cast<const s16x8*>(
                    &Bs[buf][(wn * 64 + nj * 16 + l15) * 64 + cx0]);
            #pragma unroll
            for (int mi = 0; mi < 2; ++mi)
                #pragma unroll
                for (int nj = 0; nj < 4; ++nj)
                    acc[mi][nj] = __builtin_amdgcn_mfma_f32_16x16x32_bf16(av[mi], bv[nj], acc[mi][nj], 0, 0, 0);
        }
        buf ^= 1;
    }

    #pragma unroll
    for (int nj = 0; nj < 4; ++nj) {
        int n = n0 + wn * 64 + nj * 16 + l15;
        float scale = (n < 1024) ? QSCALE : 1.0f;
        float bvs = bias[n] * scale;
        if (n < 2048) {
            #pragma unroll
            for (int mi = 0; mi < 2; ++mi)
                #pragma unroll
                for (int i = 0; i < 4; ++i) {
                    int m = m0 + wm * 32 + mi * 16 + g * 4 + i;
                    C[(size_t)m * 2048 + n] = f2bf(acc[mi][nj][i] * scale + bvs);
                }
        } else {
            int hd = n - 2048;                       // h*64 + d
            #pragma unroll
            for (int mi = 0; mi < 2; ++mi)
                #pragma unroll
                for (int i = 0; i < 4; ++i) {
                    int m = m0 + wm * 32 + mi * 16 + g * 4 + i;
                    int b = m >> 10, t = m & 1023;
                    vt[((size_t)(b * 16 + (hd >> 6)) * 64 + (hd & 63)) * 1024 + t] =
                        f2bf(acc[mi][nj][i] + bvs);
                }
        }
    }
}

// ---------------- flash attention: per (b, h, 64-row q-tile) ----------------
// Address-hoisted: staging pointers advance by constant strides; all LDS
// byte-offsets precomputed per-lane (statically indexed -- rule #20 safe).
__global__ __launch_bounds__(256, 4) void k_flash(const u16* __restrict__ qk,
                                                  const u16* __restrict__ vt,
                                                  float* __restrict__ ml,
                                                  float* __restrict__ cmean) {
    const int id = blockIdx.x + 16 * (blockIdx.y + 16 * blockIdx.z);
    const int x = id & 7, kq = id >> 3;
    const int gbh = x * 8 + (kq >> 4);
    const int qt = kq & 15;
    const int b = gbh >> 4, h = gbh & 15;
    const int q0 = qt * 64;
    const int tid = threadIdx.x, lane = tid & 63, w = tid >> 6;
    const int g = lane >> 4, l15 = lane & 15;
    __shared__ __attribute__((aligned(16))) u16 Ks[2][64 * 64];
    __shared__ __attribute__((aligned(16))) u16 Vt[2][64 * 64];
    __shared__ __attribute__((aligned(16))) u16 Ps[4][16 * 64];

    const size_t rowQ = (size_t)(b * 1024 + q0 + w * 16 + l15) * 2048 + h * 64;
    const s16x8 qa0 = *reinterpret_cast<const s16x8*>(qk + rowQ + g * 8);
    const s16x8 qa1 = *reinterpret_cast<const s16x8*>(qk + rowQ + 32 + g * 8);
    const s16x8 onesv = { (short)0x3F80, (short)0x3F80, (short)0x3F80, (short)0x3F80,
                          (short)0x3F80, (short)0x3F80, (short)0x3F80, (short)0x3F80 };

    const int cA = tid, cB = tid + 256;
    const int rowA = cA >> 3, jA = cA & 7, rowB = cB >> 3, jB = cB & 7;
    const u16* kbase0 = qk + (size_t)(b * 1024) * 2048 + 1024 + h * 64;
    const u16* vtb = vt + (size_t)(b * 16 + h) * 65536;

    // hoisted global staging pointers (kt=0 positions)
    const u16* gKA = kbase0 + (size_t)rowA * 2048 + ((jA ^ (rowA & 7)) * 8);
    const u16* gKB = kbase0 + (size_t)rowB * 2048 + ((jB ^ (rowB & 7)) * 8);
    const u16* gVA = vtb + (size_t)rowA * 1024 + ((jA ^ (rowA & 7)) * 8);
    const u16* gVB = vtb + (size_t)rowB * 1024 + ((jB ^ (rowB & 7)) * 8);
    // hoisted LDS byte destinations
    const int dKA = cA * 8, dKB = cB * 8;

    // hoisted LDS read offsets (u16 units)
    int kO[2][4], vO[2], pO[2], pW[4];
    #pragma unroll
    for (int tj = 0; tj < 4; ++tj) {
        int trow = tj * 16 + l15;
        kO[0][tj] = trow * 64 + ((g ^ (trow & 7)) * 8);
        kO[1][tj] = trow * 64 + (((4 + g) ^ (trow & 7)) * 8);
        pW[tj] = l15 * 64 + (((tj * 2 + (g >> 1)) ^ (l15 & 7)) * 8) + (g & 1) * 4;
    }
    pO[0] = l15 * 64 + ((g ^ (l15 & 7)) * 8);
    pO[1] = l15 * 64 + (((4 + g) ^ (l15 & 7)) * 8);
    vO[0] = l15 * 64 + ((g ^ (l15 & 7)) * 8);          // + nj*1024 per fragment
    vO[1] = l15 * 64 + (((4 + g) ^ (l15 & 7)) * 8);

    // stage kt=0
    __builtin_amdgcn_global_load_lds((AS1 const void*)gKA, (AS3 void*)(&Ks[0][dKA]), 16, 0, 0);
    __builtin_amdgcn_global_load_lds((AS1 const void*)gKB, (AS3 void*)(&Ks[0][dKB]), 16, 0, 0);
    __builtin_amdgcn_global_load_lds((AS1 const void*)gVA, (AS3 void*)(&Vt[0][dKA]), 16, 0, 0);
    __builtin_amdgcn_global_load_lds((AS1 const void*)gVB, (AS3 void*)(&Vt[0][dKB]), 16, 0, 0);
    gKA += 64 * 2048; gKB += 64 * 2048; gVA += 64; gVB += 64;

    f32x4 ctxa[4];
    #pragma unroll
    for (int nj = 0; nj < 4; ++nj) ctxa[nj] = (f32x4){0.f, 0.f, 0.f, 0.f};
    f32x4 lacc = (f32x4){0.f, 0.f, 0.f, 0.f};

    int buf = 0;
    for (int kt = 0; kt < 16; ++kt) {
        __syncthreads();
        if (kt < 15) {
            u16* kd = &Ks[buf ^ 1][0];
            u16* vd = &Vt[buf ^ 1][0];
            __builtin_amdgcn_global_load_lds((AS1 const void*)gKA, (AS3 void*)(kd + dKA), 16, 0, 0);
            __builtin_amdgcn_global_load_lds((AS1 const void*)gKB, (AS3 void*)(kd + dKB), 16, 0, 0);
            __builtin_amdgcn_global_load_lds((AS1 const void*)gVA, (AS3 void*)(vd + dKA), 16, 0, 0);
            __builtin_amdgcn_global_load_lds((AS1 const void*)gVB, (AS3 void*)(vd + dKB), 16, 0, 0);
            gKA += 64 * 2048; gKB += 64 * 2048; gVA += 64; gVB += 64;
        }
        const u16* Kb = &Ks[buf][0];
        const u16* Vb = &Vt[buf][0];
        u16* Pw = &Ps[w][0];

        f32x4 sc[4];
        #pragma unroll
        for (int tj = 0; tj < 4; ++tj) sc[tj] = (f32x4){0.f, 0.f, 0.f, 0.f};
        __builtin_amdgcn_s_setprio(1);
        #pragma unroll
        for (int kki = 0; kki < 2; ++kki) {
            s16x8 qa = kki ? qa1 : qa0;
            #pragma unroll
            for (int tj = 0; tj < 4; ++tj) {
                s16x8 kb = *reinterpret_cast<const s16x8*>(Kb + kO[kki][tj]);
                sc[tj] = __builtin_amdgcn_mfma_f32_16x16x32_bf16(kb, qa, sc[tj], 0, 0, 0);
            }
        }
        __builtin_amdgcn_s_setprio(0);

        // softmax numerators (shift 0)
        #pragma unroll
        for (int tj = 0; tj < 4; ++tj)
            #pragma unroll
            for (int i = 0; i < 4; ++i)
                sc[tj][i] = exp2f(sc[tj][i]);

        // P -> LDS via v_cvt_pk_bf16_f32
        #pragma unroll
        for (int tj = 0; tj < 4; ++tj) {
            unsigned pk01, pk23;
            asm("v_cvt_pk_bf16_f32 %0, %1, %2" : "=v"(pk01) : "v"(sc[tj][0]), "v"(sc[tj][1]));
            asm("v_cvt_pk_bf16_f32 %0, %1, %2" : "=v"(pk23) : "v"(sc[tj][2]), "v"(sc[tj][3]));
            uint2 pk = { pk01, pk23 };
            *reinterpret_cast<uint2*>(Pw + pW[tj]) = pk;
        }

        __builtin_amdgcn_s_setprio(1);
        #pragma unroll
        for (int kki = 0; kki < 2; ++kki) {
            s16x8 pa = *reinterpret_cast<const s16x8*>(Pw + pO[kki]);
            lacc = __builtin_amdgcn_mfma_f32_16x16x32_bf16(pa, onesv, lacc, 0, 0, 0);
            #pragma unroll
            for (int nj = 0; nj < 4; ++nj) {
                s16x8 vb = *reinterpret_cast<const s16x8*>(Vb + nj * 1024 + vO[kki]);
                ctxa[nj] = __builtin_amdgcn_mfma_f32_16x16x32_bf16(pa, vb, ctxa[nj], 0, 0, 0);
            }
        }
        __builtin_amdgcn_s_setprio(0);
        buf ^= 1;
    }

    float inv_i[4];
    #pragma unroll
    for (int i = 0; i < 4; ++i) {
        inv_i[i] = 1.0f / lacc[i];
        if (l15 == 0)
            ml[(size_t)(b * 16 + h) * 1024 + q0 + w * 16 + g * 4 + i] = inv_i[i] * 0.0625f;
    }

    #pragma unroll
    for (int nj = 0; nj < 4; ++nj) {
        float s = ctxa[nj][0] * inv_i[0] + ctxa[nj][1] * inv_i[1]
                + ctxa[nj][2] * inv_i[2] + ctxa[nj][3] * inv_i[3];
        s += __shfl_xor(s, 16);
        s += __shfl_xor(s, 32);
        if (g == 0)
            atomicAdd(&cmean[b * 1024 + h * 64 + nj * 16 + l15], s * (1.0f / 1024.0f));
    }
}

// ---------------- attn_weights: mean over heads, 2 s-tiles per block ----------------
__global__ __launch_bounds__(256, 4) void k_attnw(const u16* __restrict__ qk,
                                                  const float* __restrict__ ml,
                                                  float* __restrict__ attnw) {
    const int tt = blockIdx.x, stp = blockIdx.y, b = blockIdx.z;
    const int s0a = stp * 128, t0 = tt * 64;
    const int tid = threadIdx.x, lane = tid & 63, w = tid >> 6;
    const int g = lane >> 4, l15 = lane & 15;
    __shared__ __attribute__((aligned(16))) u16 Ks[2][64 * 64];
    __shared__ float mls[16][128];

    #pragma unroll
    for (int r = 0; r < 8; ++r) {
        int idx = tid + r * 256;
        int hh = idx >> 7, row = idx & 127;
        mls[hh][row] = ml[(size_t)(b * 16 + hh) * 1024 + s0a + row];
    }

    const int cA = tid, cB = tid + 256;
    const int rowA = cA >> 3, jA = cA & 7, rowB = cB >> 3, jB = cB & 7;
    const u16* kbase = qk + (size_t)(b * 1024 + t0) * 2048 + 1024;
    const size_t rowQa = (size_t)(b * 1024 + s0a + w * 16 + l15) * 2048;
    const size_t rowQb = rowQa + (size_t)64 * 2048;

    __builtin_amdgcn_global_load_lds((AS1 const void*)(kbase + (size_t)rowA * 2048 + ((jA ^ (rowA & 7)) * 8)),
                                     (AS3 void*)(&Ks[0][cA * 8]), 16, 0, 0);
    __builtin_amdgcn_global_load_lds((AS1 const void*)(kbase + (size_t)rowB * 2048 + ((jB ^ (rowB & 7)) * 8)),
                                     (AS3 void*)(&Ks[0][cB * 8]), 16, 0, 0);
    s16x8 qcA0 = *reinterpret_cast<const s16x8*>(qk + rowQa + g * 8);
    s16x8 qcA1 = *reinterpret_cast<const s16x8*>(qk + rowQa + 32 + g * 8);
    s16x8 qcB0 = *reinterpret_cast<const s16x8*>(qk + rowQb + g * 8);
    s16x8 qcB1 = *reinterpret_cast<const s16x8*>(qk + rowQb + 32 + g * 8);

    f32x4 accA[4], accB[4];
    #pragma unroll
    for (int tj = 0; tj < 4; ++tj) {
        accA[tj] = (f32x4){0.f, 0.f, 0.f, 0.f};
        accB[tj] = (f32x4){0.f, 0.f, 0.f, 0.f};
    }

    int buf = 0;
    for (int h = 0; h < 16; ++h) {
        __syncthreads();
        s16x8 qnA0, qnA1, qnB0, qnB1;
        if (h < 15) {
            const u16* kb2 = kbase + (h + 1) * 64;
            __builtin_amdgcn_global_load_lds((AS1 const void*)(kb2 + (size_t)rowA * 2048 + ((jA ^ (rowA & 7)) * 8)),
                                             (AS3 void*)(&Ks[buf ^ 1][cA * 8]), 16, 0, 0);
            __builtin_amdgcn_global_load_lds((AS1 const void*)(kb2 + (size_t)rowB * 2048 + ((jB ^ (rowB & 7)) * 8)),
                                             (AS3 void*)(&Ks[buf ^ 1][cB * 8]), 16, 0, 0);
            qnA0 = *reinterpret_cast<const s16x8*>(qk + rowQa + (h + 1) * 64 + g * 8);
            qnA1 = *reinterpret_cast<const s16x8*>(qk + rowQa + (h + 1) * 64 + 32 + g * 8);
            qnB0 = *reinterpret_cast<const s16x8*>(qk + rowQb + (h + 1) * 64 + g * 8);
            qnB1 = *reinterpret_cast<const s16x8*>(qk + rowQb + (h + 1) * 64 + 32 + g * 8);
        }

        f32x4 scA[4], scB[4];
        #pragma unroll
        for (int tj = 0; tj < 4; ++tj) {
            scA[tj] = (f32x4){0.f, 0.f, 0.f, 0.f};
            scB[tj] = (f32x4){0.f, 0.f, 0.f, 0.f};
        }
        #pragma unroll
        for (int kk = 0; kk < 64; kk += 32) {
            s16x8 qaA = kk ? qcA1 : qcA0;
            s16x8 qaB = kk ? qcB1 : qcB0;
            #pragma unroll
            for (int tj = 0; tj < 4; ++tj) {
                int trow = tj * 16 + l15;
                s16x8 kb = *reinterpret_cast<const s16x8*>(
                    &Ks[buf][trow * 64 + ((((kk >> 3) + g) ^ (trow & 7)) * 8)]);
                scA[tj] = __builtin_amdgcn_mfma_f32_16x16x32_bf16(qaA, kb, scA[tj], 0, 0, 0);
                scB[tj] = __builtin_amdgcn_mfma_f32_16x16x32_bf16(qaB, kb, scB[tj], 0, 0, 0);
            }
        }
        #pragma unroll
        for (int i = 0; i < 4; ++i) {
            int row = w * 16 + g * 4 + i;
            float Ma = mls[h][row];
            float Mb = mls[h][64 + row];
            #pragma unroll
            for (int tj = 0; tj < 4; ++tj) {
                accA[tj][i] += exp2f(scA[tj][i]) * Ma;
                accB[tj][i] += exp2f(scB[tj][i]) * Mb;
            }
        }
        qcA0 = qnA0; qcA1 = qnA1; qcB0 = qnB0; qcB1 = qnB1;
        buf ^= 1;
    }

    #pragma unroll
    for (int i = 0; i < 4; ++i) {
        int rowa = s0a + w * 16 + g * 4 + i;
        #pragma unroll
        for (int tj = 0; tj < 4; ++tj) {
            attnw[(size_t)(b * 1024 + rowa) * 1024 + t0 + tj * 16 + l15] = accA[tj][i];
            attnw[(size_t)(b * 1024 + rowa + 64) * 1024 + t0 + tj * 16 + l15] = accB[tj][i];
        }
    }
}

// ---------------- out-proj on the mean (parallelized): 64 blk x 256 thr ----------------
__global__ __launch_bounds__(256) void k_outproj(const float* __restrict__ cmean,
                                                 const float* __restrict__ wout,
                                                 const float* __restrict__ bias,
                                                 float* __restrict__ out) {
    __shared__ float cs[4096];
    #pragma unroll
    for (int r = 0; r < 16; ++r) {
        int idx = threadIdx.x + r * 256;
        cs[idx] = cmean[idx];
    }
    __syncthreads();
    int G = blockIdx.x * 256 + threadIdx.x;   // 0..16383
    int e = G >> 4, ks = G & 15;
    const float4* wr = reinterpret_cast<const float4*>(wout) + (size_t)e * 256 + ks * 16;
    const float4* c0 = reinterpret_cast<const float4*>(&cs[0]) + ks * 16;
    const float4* c1 = reinterpret_cast<const float4*>(&cs[1024]) + ks * 16;
    const float4* c2 = reinterpret_cast<const float4*>(&cs[2048]) + ks * 16;
    const float4* c3 = reinterpret_cast<const float4*>(&cs[3072]) + ks * 16;
    float s0 = 0.f, s1 = 0.f, s2 = 0.f, s3 = 0.f;
    #pragma unroll
    for (int k = 0; k < 16; ++k) {
        float4 wv = wr[k];
        float4 a = c0[k], b = c1[k], c = c2[k], d = c3[k];
        s0 += a.x * wv.x + a.y * wv.y + a.z * wv.z + a.w * wv.w;
        s1 += b.x * wv.x + b.y * wv.y + b.z * wv.z + b.w * wv.w;
        s2 += c.x * wv.x + c.y * wv.y + c.z * wv.z + c.w * wv.w;
        s3 += d.x * wv.x + d.y * wv.y + d.z * wv.z + d.w * wv.w;
    }
    #pragma unroll
    for (int off = 1; off < 16; off <<= 1) {
        s0 += __shfl_xor(s0, off);
        s1 += __shfl_xor(s1, off);
        s2 += __shfl_xor(s2, off);
        s3 += __shfl_xor(s3, off);
    }
    if (ks == 0) {
        float bv = bias[e];
        out[e]        = s0 + bv;
        out[1024 + e] = s1 + bv;
        out[2048 + e] = s2 + bv;
        out[3072 + e] = s3 + bv;
    }
}

// ---------------- launch ----------------
extern "C" void kernel_launch(void* const* d_in, const int* in_sizes, int n_in,
                              void* d_out, int out_size, void* d_ws, size_t ws_size,
                              hipStream_t stream) {
    const float* lstm = (const float*)d_in[0];   // [4,1024,1024]
    const float* wqkv = (const float*)d_in[1];   // [3072,1024]
    const float* bqkv = (const float*)d_in[2];   // [3072]
    const float* wout = (const float*)d_in[3];   // [1024,1024]
    const float* bout = (const float*)d_in[4];   // [1024]
    float* out = (float*)d_out;                  // [4096 ctxvec | 4*1024*1024 attn]

    char* ws = (char*)d_ws;
    u16*   Xbf   = (u16*)(ws);                          // 8 MiB
    u16*   Wqkvb = (u16*)(ws + 8u  * 1024 * 1024);      // 6 MiB
    u16*   qkbuf = (u16*)(ws + 16u * 1024 * 1024);      // 16 MiB  [4096][2048]
    u16*   vtg   = (u16*)(ws + 32u * 1024 * 1024);      // 8 MiB   [64][64][1024]
    float* ml    = (float*)(ws + 40u * 1024 * 1024);    // 256 KiB (invl/16)
    float* cmean = (float*)(ws + 41u * 1024 * 1024);    // 16 KiB  [4][1024]

    k_prep<<<7168, 256, 0, stream>>>(lstm, wqkv, Xbf, Wqkvb, cmean);

    k_gemm_bt<<<dim3(24, 32), 512, 0, stream>>>(Xbf, Wqkvb, bqkv, qkbuf, vtg);
    k_flash<<<dim3(16, 16, 4), 256, 0, stream>>>(qkbuf, vtg, ml, cmean);
    k_attnw<<<dim3(16, 8, 4), 256, 0, stream>>>(qkbuf, ml, out + 4096);
    k_outproj<<<64, 256, 0, stream>>>(cmean, wout, bout, out);
}

// Round 15
// 120.372 us; speedup vs baseline: 1.0591x; 1.0035x over previous
//
#include <hip/hip_runtime.h>

// B=4, S=1024, E=1024, H=16, D=64.
// qk   : [4096][2048] bf16  (Q|K), Q pre-scaled by 0.125*log2(e)
// vt   : [64 bh][64 d][1024 t] bf16  (V transposed, built in GEMM epilogue)
// ml   : invl/16 (float) per (b,h,row) -- softmax shift 0 (no max tracking)
// cmean: [4][1024] fp32 = mean_s(ctx);  context_vector = cmean @ Wout^T + bias
// flash: QBLK=128 (8 waves) -- halves barrier/stage events per unit work.

typedef unsigned short u16;
using s16x8 = __attribute__((ext_vector_type(8))) short;   // 8 bf16 = 4 VGPR
using f32x4 = __attribute__((ext_vector_type(4))) float;   // MFMA C/D
using u16x4 = __attribute__((ext_vector_type(4))) unsigned short;

#define AS1 __attribute__((address_space(1)))
#define AS3 __attribute__((address_space(3)))

#define QSCALE 0.1803368801111204f   // 0.125 * log2(e)

__device__ __forceinline__ u16 f2bf(float f) {
    unsigned u = __float_as_uint(f);
    u += 0x7fffu + ((u >> 16) & 1u);   // RTN-even
    return (u16)(u >> 16);
}

// ---------------- fused fp32->bf16 converts + cmean zero ----------------
__global__ void k_prep(const float* __restrict__ X, const float* __restrict__ W1,
                       u16* __restrict__ Xb, u16* __restrict__ W1b,
                       float* __restrict__ cmean) {
    int i = blockIdx.x * blockDim.x + threadIdx.x;
    const float* src; u16* dst; int off;
    if (i < 1048576)       { src = X;  dst = Xb;  off = i; }
    else                   { src = W1; dst = W1b; off = i - 1048576; }
    float4 v = reinterpret_cast<const float4*>(src)[off];
    u16x4 o = { f2bf(v.x), f2bf(v.y), f2bf(v.z), f2bf(v.w) };
    reinterpret_cast<u16x4*>(dst)[off] = o;
    if (i < 4096) cmean[i] = 0.f;
}

// ---------------- 128x128 BT GEMM (QKV), 8 waves: T2 swizzle + XCD swz + dbuf ----------------
__global__ __launch_bounds__(512) void k_gemm_bt(
    const u16* __restrict__ A, const u16* __restrict__ B,
    const float* __restrict__ bias, u16* __restrict__ C,
    u16* __restrict__ vt) {
    const int K = 1024;
    const int nbx = gridDim.x;
    const int nwg = nbx * gridDim.y;
    const int bid = blockIdx.y * nbx + blockIdx.x;
    const int per = nwg >> 3;
    const int swz = (bid & 7) * per + (bid >> 3);
    const int n0 = (swz % nbx) * 128, m0 = (swz / nbx) * 128;
    const int tid = threadIdx.x, lane = tid & 63, w = tid >> 6;
    const int wm = w >> 1, wn = w & 1;
    const int g = lane >> 4, l15 = lane & 15;
    __shared__ __attribute__((aligned(16))) u16 As[2][128 * 64];
    __shared__ __attribute__((aligned(16))) u16 Bs[2][128 * 64];

    f32x4 acc[2][4];
    #pragma unroll
    for (int mi = 0; mi < 2; ++mi)
        #pragma unroll
        for (int nj = 0; nj < 4; ++nj) acc[mi][nj] = (f32x4){0.f, 0.f, 0.f, 0.f};

    auto STAGE = [&](int k0, int sb) {
        #pragma unroll
        for (int r = 0; r < 2; ++r) {          // 1024 chunks over 512 threads
            int c = tid + r * 512;
            int row = c >> 3, j = c & 7;
            int js = j ^ (row & 7);            // pre-swizzled source chunk (rule #21)
            __builtin_amdgcn_global_load_lds(
                (AS1 const void*)(A + (size_t)(m0 + row) * K + k0 + js * 8),
                (AS3 void*)(&As[sb][c * 8]), 16, 0, 0);
            __builtin_amdgcn_global_load_lds(
                (AS1 const void*)(B + (size_t)(n0 + row) * K + k0 + js * 8),
                (AS3 void*)(&Bs[sb][c * 8]), 16, 0, 0);
        }
    };

    STAGE(0, 0);
    int buf = 0;
    for (int k0 = 0; k0 < K; k0 += 64) {
        __syncthreads();                       // buf ready; buf^1 free
        if (k0 + 64 < K) STAGE(k0 + 64, buf ^ 1);
        #pragma unroll
        for (int kk = 0; kk < 64; kk += 32) {
            const int cx0 = (((kk >> 3) + g) ^ (l15 & 7)) * 8;   // swizzled read chunk
            s16x8 av[2], bv[4];
            #pragma unroll
            for (int mi = 0; mi < 2; ++mi)
                av[mi] = *reinterpret_cast<const s16x8*>(
                    &As[buf][(wm * 32 + mi * 16 + l15) * 64 + cx0]);
            #pragma unroll
            for (int nj = 0; nj < 4; ++nj)
                bv[nj] = *reinterpret_cast<const s16x8*>(
                    &Bs[buf][(wn * 64 + nj * 16 + l15) * 64 + cx0]);
            #pragma unroll
            for (int mi = 0; mi < 2; ++mi)
                #pragma unroll
                for (int nj = 0; nj < 4; ++nj)
                    acc[mi][nj] = __builtin_amdgcn_mfma_f32_16x16x32_bf16(av[mi], bv[nj], acc[mi][nj], 0, 0, 0);
        }
        buf ^= 1;
    }

    #pragma unroll
    for (int nj = 0; nj < 4; ++nj) {
        int n = n0 + wn * 64 + nj * 16 + l15;
        float scale = (n < 1024) ? QSCALE : 1.0f;
        float bvs = bias[n] * scale;
        if (n < 2048) {
            #pragma unroll
            for (int mi = 0; mi < 2; ++mi)
                #pragma unroll
                for (int i = 0; i < 4; ++i) {
                    int m = m0 + wm * 32 + mi * 16 + g * 4 + i;
                    C[(size_t)m * 2048 + n] = f2bf(acc[mi][nj][i] * scale + bvs);
                }
        } else {
            int hd = n - 2048;                       // h*64 + d
            #pragma unroll
            for (int mi = 0; mi < 2; ++mi)
                #pragma unroll
                for (int i = 0; i < 4; ++i) {
                    int m = m0 + wm * 32 + mi * 16 + g * 4 + i;
                    int b = m >> 10, t = m & 1023;
                    vt[((size_t)(b * 16 + (hd >> 6)) * 64 + (hd & 63)) * 1024 + t] =
                        f2bf(acc[mi][nj][i] + bvs);
                }
        }
    }
}

// ---------------- flash attention: per (b, h, 128-row q-block), 8 waves ----------------
// Address-hoisted; row-sum via ones-MFMA; epilogue: ml + fp32 col-mean -> cmean.
__global__ __launch_bounds__(512, 2) void k_flash(const u16* __restrict__ qk,
                                                  const u16* __restrict__ vt,
                                                  float* __restrict__ ml,
                                                  float* __restrict__ cmean) {
    // 512 blocks: id%8 = XCD; 8 q-blocks of one (b,h) share an XCD
    const int id = blockIdx.x + 8 * (blockIdx.y + 16 * blockIdx.z);
    const int x = id & 7, k = id >> 3;          // k in 0..63
    const int gbh = x * 8 + (k >> 3);
    const int qt = k & 7;
    const int b = gbh >> 4, h = gbh & 15;
    const int q0 = qt * 128;
    const int tid = threadIdx.x, lane = tid & 63, w = tid >> 6;  // 8 waves
    const int g = lane >> 4, l15 = lane & 15;
    __shared__ __attribute__((aligned(16))) u16 Ks[2][64 * 64];
    __shared__ __attribute__((aligned(16))) u16 Vt[2][64 * 64];
    __shared__ __attribute__((aligned(16))) u16 Ps[8][16 * 64];

    const size_t rowQ = (size_t)(b * 1024 + q0 + w * 16 + l15) * 2048 + h * 64;
    const s16x8 qa0 = *reinterpret_cast<const s16x8*>(qk + rowQ + g * 8);
    const s16x8 qa1 = *reinterpret_cast<const s16x8*>(qk + rowQ + 32 + g * 8);
    const s16x8 onesv = { (short)0x3F80, (short)0x3F80, (short)0x3F80, (short)0x3F80,
                          (short)0x3F80, (short)0x3F80, (short)0x3F80, (short)0x3F80 };

    // staging: 512 threads cover one 64x64 tile (16B each)
    const int rowA = tid >> 3, jA = tid & 7;
    const int dKA = tid * 8;                    // linear LDS dest (u16 units)
    const u16* kbase0 = qk + (size_t)(b * 1024) * 2048 + 1024 + h * 64;
    const u16* vtb = vt + (size_t)(b * 16 + h) * 65536;
    const u16* gKA = kbase0 + (size_t)rowA * 2048 + ((jA ^ (rowA & 7)) * 8);
    const u16* gVA = vtb + (size_t)rowA * 1024 + ((jA ^ (rowA & 7)) * 8);

    // hoisted LDS read offsets (u16 units)
    int kO[2][4], vO[2], pO[2], pW[4];
    #pragma unroll
    for (int tj = 0; tj < 4; ++tj) {
        int trow = tj * 16 + l15;
        kO[0][tj] = trow * 64 + ((g ^ (trow & 7)) * 8);
        kO[1][tj] = trow * 64 + (((4 + g) ^ (trow & 7)) * 8);
        pW[tj] = l15 * 64 + (((tj * 2 + (g >> 1)) ^ (l15 & 7)) * 8) + (g & 1) * 4;
    }
    pO[0] = l15 * 64 + ((g ^ (l15 & 7)) * 8);
    pO[1] = l15 * 64 + (((4 + g) ^ (l15 & 7)) * 8);
    vO[0] = pO[0];
    vO[1] = pO[1];

    // stage kt=0
    __builtin_amdgcn_global_load_lds((AS1 const void*)gKA, (AS3 void*)(&Ks[0][dKA]), 16, 0, 0);
    __builtin_amdgcn_global_load_lds((AS1 const void*)gVA, (AS3 void*)(&Vt[0][dKA]), 16, 0, 0);
    gKA += 64 * 2048; gVA += 64;

    f32x4 ctxa[4];
    #pragma unroll
    for (int nj = 0; nj < 4; ++nj) ctxa[nj] = (f32x4){0.f, 0.f, 0.f, 0.f};
    f32x4 lacc = (f32x4){0.f, 0.f, 0.f, 0.f};

    int buf = 0;
    for (int kt = 0; kt < 16; ++kt) {
        __syncthreads();
        if (kt < 15) {
            __builtin_amdgcn_global_load_lds((AS1 const void*)gKA, (AS3 void*)(&Ks[buf ^ 1][dKA]), 16, 0, 0);
            __builtin_amdgcn_global_load_lds((AS1 const void*)gVA, (AS3 void*)(&Vt[buf ^ 1][dKA]), 16, 0, 0);
            gKA += 64 * 2048; gVA += 64;
        }
        const u16* Kb = &Ks[buf][0];
        const u16* Vb = &Vt[buf][0];
        u16* Pw = &Ps[w][0];

        f32x4 sc[4];
        #pragma unroll
        for (int tj = 0; tj < 4; ++tj) sc[tj] = (f32x4){0.f, 0.f, 0.f, 0.f};
        __builtin_amdgcn_s_setprio(1);
        #pragma unroll
        for (int kki = 0; kki < 2; ++kki) {
            s16x8 qa = kki ? qa1 : qa0;
            #pragma unroll
            for (int tj = 0; tj < 4; ++tj) {
                s16x8 kb = *reinterpret_cast<const s16x8*>(Kb + kO[kki][tj]);
                sc[tj] = __builtin_amdgcn_mfma_f32_16x16x32_bf16(kb, qa, sc[tj], 0, 0, 0);
            }
        }
        __builtin_amdgcn_s_setprio(0);

        // softmax numerators (shift 0)
        #pragma unroll
        for (int tj = 0; tj < 4; ++tj)
            #pragma unroll
            for (int i = 0; i < 4; ++i)
                sc[tj][i] = exp2f(sc[tj][i]);

        // P -> LDS via v_cvt_pk_bf16_f32
        #pragma unroll
        for (int tj = 0; tj < 4; ++tj) {
            unsigned pk01, pk23;
            asm("v_cvt_pk_bf16_f32 %0, %1, %2" : "=v"(pk01) : "v"(sc[tj][0]), "v"(sc[tj][1]));
            asm("v_cvt_pk_bf16_f32 %0, %1, %2" : "=v"(pk23) : "v"(sc[tj][2]), "v"(sc[tj][3]));
            uint2 pk = { pk01, pk23 };
            *reinterpret_cast<uint2*>(Pw + pW[tj]) = pk;
        }

        __builtin_amdgcn_s_setprio(1);
        #pragma unroll
        for (int kki = 0; kki < 2; ++kki) {
            s16x8 pa = *reinterpret_cast<const s16x8*>(Pw + pO[kki]);
            lacc = __builtin_amdgcn_mfma_f32_16x16x32_bf16(pa, onesv, lacc, 0, 0, 0);
            #pragma unroll
            for (int nj = 0; nj < 4; ++nj) {
                s16x8 vb = *reinterpret_cast<const s16x8*>(Vb + nj * 1024 + vO[kki]);
                ctxa[nj] = __builtin_amdgcn_mfma_f32_16x16x32_bf16(pa, vb, ctxa[nj], 0, 0, 0);
            }
        }
        __builtin_amdgcn_s_setprio(0);
        buf ^= 1;
    }

    float inv_i[4];
    #pragma unroll
    for (int i = 0; i < 4; ++i) {
        inv_i[i] = 1.0f / lacc[i];
        if (l15 == 0)
            ml[(size_t)(b * 16 + h) * 1024 + q0 + w * 16 + g * 4 + i] = inv_i[i] * 0.0625f;
    }

    #pragma unroll
    for (int nj = 0; nj < 4; ++nj) {
        float s = ctxa[nj][0] * inv_i[0] + ctxa[nj][1] * inv_i[1]
                + ctxa[nj][2] * inv_i[2] + ctxa[nj][3] * inv_i[3];
        s += __shfl_xor(s, 16);
        s += __shfl_xor(s, 32);
        if (g == 0)
            atomicAdd(&cmean[b * 1024 + h * 64 + nj * 16 + l15], s * (1.0f / 1024.0f));
    }
}

// ---------------- attn_weights: mean over heads, 2 s-tiles per block ----------------
__global__ __launch_bounds__(256, 4) void k_attnw(const u16* __restrict__ qk,
                                                  const float* __restrict__ ml,
                                                  float* __restrict__ attnw) {
    const int tt = blockIdx.x, stp = blockIdx.y, b = blockIdx.z;
    const int s0a = stp * 128, t0 = tt * 64;
    const int tid = threadIdx.x, lane = tid & 63, w = tid >> 6;
    const int g = lane >> 4, l15 = lane & 15;
    __shared__ __attribute__((aligned(16))) u16 Ks[2][64 * 64];
    __shared__ float mls[16][128];

    #pragma unroll
    for (int r = 0; r < 8; ++r) {
        int idx = tid + r * 256;
        int hh = idx >> 7, row = idx & 127;
        mls[hh][row] = ml[(size_t)(b * 16 + hh) * 1024 + s0a + row];
    }

    const int cA = tid, cB = tid + 256;
    const int rowA = cA >> 3, jA = cA & 7, rowB = cB >> 3, jB = cB & 7;
    const u16* kbase = qk + (size_t)(b * 1024 + t0) * 2048 + 1024;
    const size_t rowQa = (size_t)(b * 1024 + s0a + w * 16 + l15) * 2048;
    const size_t rowQb = rowQa + (size_t)64 * 2048;

    __builtin_amdgcn_global_load_lds((AS1 const void*)(kbase + (size_t)rowA * 2048 + ((jA ^ (rowA & 7)) * 8)),
                                     (AS3 void*)(&Ks[0][cA * 8]), 16, 0, 0);
    __builtin_amdgcn_global_load_lds((AS1 const void*)(kbase + (size_t)rowB * 2048 + ((jB ^ (rowB & 7)) * 8)),
                                     (AS3 void*)(&Ks[0][cB * 8]), 16, 0, 0);
    s16x8 qcA0 = *reinterpret_cast<const s16x8*>(qk + rowQa + g * 8);
    s16x8 qcA1 = *reinterpret_cast<const s16x8*>(qk + rowQa + 32 + g * 8);
    s16x8 qcB0 = *reinterpret_cast<const s16x8*>(qk + rowQb + g * 8);
    s16x8 qcB1 = *reinterpret_cast<const s16x8*>(qk + rowQb + 32 + g * 8);

    f32x4 accA[4], accB[4];
    #pragma unroll
    for (int tj = 0; tj < 4; ++tj) {
        accA[tj] = (f32x4){0.f, 0.f, 0.f, 0.f};
        accB[tj] = (f32x4){0.f, 0.f, 0.f, 0.f};
    }

    int buf = 0;
    for (int h = 0; h < 16; ++h) {
        __syncthreads();
        s16x8 qnA0, qnA1, qnB0, qnB1;
        if (h < 15) {
            const u16* kb2 = kbase + (h + 1) * 64;
            __builtin_amdgcn_global_load_lds((AS1 const void*)(kb2 + (size_t)rowA * 2048 + ((jA ^ (rowA & 7)) * 8)),
                                             (AS3 void*)(&Ks[buf ^ 1][cA * 8]), 16, 0, 0);
            __builtin_amdgcn_global_load_lds((AS1 const void*)(kb2 + (size_t)rowB * 2048 + ((jB ^ (rowB & 7)) * 8)),
                                             (AS3 void*)(&Ks[buf ^ 1][cB * 8]), 16, 0, 0);
            qnA0 = *reinterpret_cast<const s16x8*>(qk + rowQa + (h + 1) * 64 + g * 8);
            qnA1 = *reinterpret_cast<const s16x8*>(qk + rowQa + (h + 1) * 64 + 32 + g * 8);
            qnB0 = *reinterpret_cast<const s16x8*>(qk + rowQb + (h + 1) * 64 + g * 8);
            qnB1 = *reinterpret_cast<const s16x8*>(qk + rowQb + (h + 1) * 64 + 32 + g * 8);
        }

        f32x4 scA[4], scB[4];
        #pragma unroll
        for (int tj = 0; tj < 4; ++tj) {
            scA[tj] = (f32x4){0.f, 0.f, 0.f, 0.f};
            scB[tj] = (f32x4){0.f, 0.f, 0.f, 0.f};
        }
        #pragma unroll
        for (int kk = 0; kk < 64; kk += 32) {
            s16x8 qaA = kk ? qcA1 : qcA0;
            s16x8 qaB = kk ? qcB1 : qcB0;
            #pragma unroll
            for (int tj = 0; tj < 4; ++tj) {
                int trow = tj * 16 + l15;
                s16x8 kb = *reinterpret_cast<const s16x8*>(
                    &Ks[buf][trow * 64 + ((((kk >> 3) + g) ^ (trow & 7)) * 8)]);
                scA[tj] = __builtin_amdgcn_mfma_f32_16x16x32_bf16(qaA, kb, scA[tj], 0, 0, 0);
                scB[tj] = __builtin_amdgcn_mfma_f32_16x16x32_bf16(qaB, kb, scB[tj], 0, 0, 0);
            }
        }
        #pragma unroll
        for (int i = 0; i < 4; ++i) {
            int row = w * 16 + g * 4 + i;
            float Ma = mls[h][row];
            float Mb = mls[h][64 + row];
            #pragma unroll
            for (int tj = 0; tj < 4; ++tj) {
                accA[tj][i] += exp2f(scA[tj][i]) * Ma;
                accB[tj][i] += exp2f(scB[tj][i]) * Mb;
            }
        }
        qcA0 = qnA0; qcA1 = qnA1; qcB0 = qnB0; qcB1 = qnB1;
        buf ^= 1;
    }

    #pragma unroll
    for (int i = 0; i < 4; ++i) {
        int rowa = s0a + w * 16 + g * 4 + i;
        #pragma unroll
        for (int tj = 0; tj < 4; ++tj) {
            attnw[(size_t)(b * 1024 + rowa) * 1024 + t0 + tj * 16 + l15] = accA[tj][i];
            attnw[(size_t)(b * 1024 + rowa + 64) * 1024 + t0 + tj * 16 + l15] = accB[tj][i];
        }
    }
}

// ---------------- out-proj on the mean (parallelized): 64 blk x 256 thr ----------------
__global__ __launch_bounds__(256) void k_outproj(const float* __restrict__ cmean,
                                                 const float* __restrict__ wout,
                                                 const float* __restrict__ bias,
                                                 float* __restrict__ out) {
    __shared__ float cs[4096];
    #pragma unroll
    for (int r = 0; r < 16; ++r) {
        int idx = threadIdx.x + r * 256;
        cs[idx] = cmean[idx];
    }
    __syncthreads();
    int G = blockIdx.x * 256 + threadIdx.x;   // 0..16383
    int e = G >> 4, ks = G & 15;
    const float4* wr = reinterpret_cast<const float4*>(wout) + (size_t)e * 256 + ks * 16;
    const float4* c0 = reinterpret_cast<const float4*>(&cs[0]) + ks * 16;
    const float4* c1 = reinterpret_cast<const float4*>(&cs[1024]) + ks * 16;
    const float4* c2 = reinterpret_cast<const float4*>(&cs[2048]) + ks * 16;
    const float4* c3 = reinterpret_cast<const float4*>(&cs[3072]) + ks * 16;
    float s0 = 0.f, s1 = 0.f, s2 = 0.f, s3 = 0.f;
    #pragma unroll
    for (int k = 0; k < 16; ++k) {
        float4 wv = wr[k];
        float4 a = c0[k], b = c1[k], c = c2[k], d = c3[k];
        s0 += a.x * wv.x + a.y * wv.y + a.z * wv.z + a.w * wv.w;
        s1 += b.x * wv.x + b.y * wv.y + b.z * wv.z + b.w * wv.w;
        s2 += c.x * wv.x + c.y * wv.y + c.z * wv.z + c.w * wv.w;
        s3 += d.x * wv.x + d.y * wv.y + d.z * wv.z + d.w * wv.w;
    }
    #pragma unroll
    for (int off = 1; off < 16; off <<= 1) {
        s0 += __shfl_xor(s0, off);
        s1 += __shfl_xor(s1, off);
        s2 += __shfl_xor(s2, off);
        s3 += __shfl_xor(s3, off);
    }
    if (ks == 0) {
        float bv = bias[e];
        out[e]        = s0 + bv;
        out[1024 + e] = s1 + bv;
        out[2048 + e] = s2 + bv;
        out[3072 + e] = s3 + bv;
    }
}

// ---------------- launch ----------------
extern "C" void kernel_launch(void* const* d_in, const int* in_sizes, int n_in,
                              void* d_out, int out_size, void* d_ws, size_t ws_size,
                              hipStream_t stream) {
    const float* lstm = (const float*)d_in[0];   // [4,1024,1024]
    const float* wqkv = (const float*)d_in[1];   // [3072,1024]
    const float* bqkv = (const float*)d_in[2];   // [3072]
    const float* wout = (const float*)d_in[3];   // [1024,1024]
    const float* bout = (const float*)d_in[4];   // [1024]
    float* out = (float*)d_out;                  // [4096 ctxvec | 4*1024*1024 attn]

    char* ws = (char*)d_ws;
    u16*   Xbf   = (u16*)(ws);                          // 8 MiB
    u16*   Wqkvb = (u16*)(ws + 8u  * 1024 * 1024);      // 6 MiB
    u16*   qkbuf = (u16*)(ws + 16u * 1024 * 1024);      // 16 MiB  [4096][2048]
    u16*   vtg   = (u16*)(ws + 32u * 1024 * 1024);      // 8 MiB   [64][64][1024]
    float* ml    = (float*)(ws + 40u * 1024 * 1024);    // 256 KiB (invl/16)
    float* cmean = (float*)(ws + 41u * 1024 * 1024);    // 16 KiB  [4][1024]

    k_prep<<<7168, 256, 0, stream>>>(lstm, wqkv, Xbf, Wqkvb, cmean);

    k_gemm_bt<<<dim3(24, 32), 512, 0, stream>>>(Xbf, Wqkvb, bqkv, qkbuf, vtg);
    k_flash<<<dim3(8, 16, 4), 512, 0, stream>>>(qkbuf, vtg, ml, cmean);
    k_attnw<<<dim3(16, 8, 4), 256, 0, stream>>>(qkbuf, ml, out + 4096);
    k_outproj<<<64, 256, 0, stream>>>(cmean, wout, bout, out);
}

// Round 16
// 113.949 us; speedup vs baseline: 1.1188x; 1.0564x over previous
//
#include <hip/hip_runtime.h>

// B=4, S=1024, E=1024, H=16, D=64.
// qk   : [4096][2048] bf16  (Q|K), Q pre-scaled by 0.125*log2(e)
// vt   : [64 bh][64 d][1024 t] bf16  (V transposed, built in GEMM epilogue)
// ml   : invl/16 (float) per (b,h,row) -- softmax shift 0 (no max tracking)
// cmean: [4][1024] fp32 = mean_s(ctx);  context_vector = cmean @ Wout^T + bias
// flash: T15 double-pipeline -- QK^T(kt) overlaps softmax+PV(kt-1); V triple-buf.

typedef unsigned short u16;
using s16x8 = __attribute__((ext_vector_type(8))) short;   // 8 bf16 = 4 VGPR
using f32x4 = __attribute__((ext_vector_type(4))) float;   // MFMA C/D
using u16x4 = __attribute__((ext_vector_type(4))) unsigned short;

#define AS1 __attribute__((address_space(1)))
#define AS3 __attribute__((address_space(3)))

#define QSCALE 0.1803368801111204f   // 0.125 * log2(e)

__device__ __forceinline__ u16 f2bf(float f) {
    unsigned u = __float_as_uint(f);
    u += 0x7fffu + ((u >> 16) & 1u);   // RTN-even
    return (u16)(u >> 16);
}

// ---------------- fused fp32->bf16 converts + cmean zero ----------------
__global__ void k_prep(const float* __restrict__ X, const float* __restrict__ W1,
                       u16* __restrict__ Xb, u16* __restrict__ W1b,
                       float* __restrict__ cmean) {
    int i = blockIdx.x * blockDim.x + threadIdx.x;
    const float* src; u16* dst; int off;
    if (i < 1048576)       { src = X;  dst = Xb;  off = i; }
    else                   { src = W1; dst = W1b; off = i - 1048576; }
    float4 v = reinterpret_cast<const float4*>(src)[off];
    u16x4 o = { f2bf(v.x), f2bf(v.y), f2bf(v.z), f2bf(v.w) };
    reinterpret_cast<u16x4*>(dst)[off] = o;
    if (i < 4096) cmean[i] = 0.f;
}

// ---------------- 128x128 BT GEMM (QKV), 8 waves: T2 swizzle + XCD swz + dbuf ----------------
__global__ __launch_bounds__(512) void k_gemm_bt(
    const u16* __restrict__ A, const u16* __restrict__ B,
    const float* __restrict__ bias, u16* __restrict__ C,
    u16* __restrict__ vt) {
    const int K = 1024;
    const int nbx = gridDim.x;
    const int nwg = nbx * gridDim.y;
    const int bid = blockIdx.y * nbx + blockIdx.x;
    const int per = nwg >> 3;
    const int swz = (bid & 7) * per + (bid >> 3);
    const int n0 = (swz % nbx) * 128, m0 = (swz / nbx) * 128;
    const int tid = threadIdx.x, lane = tid & 63, w = tid >> 6;
    const int wm = w >> 1, wn = w & 1;
    const int g = lane >> 4, l15 = lane & 15;
    __shared__ __attribute__((aligned(16))) u16 As[2][128 * 64];
    __shared__ __attribute__((aligned(16))) u16 Bs[2][128 * 64];

    f32x4 acc[2][4];
    #pragma unroll
    for (int mi = 0; mi < 2; ++mi)
        #pragma unroll
        for (int nj = 0; nj < 4; ++nj) acc[mi][nj] = (f32x4){0.f, 0.f, 0.f, 0.f};

    auto STAGE = [&](int k0, int sb) {
        #pragma unroll
        for (int r = 0; r < 2; ++r) {          // 1024 chunks over 512 threads
            int c = tid + r * 512;
            int row = c >> 3, j = c & 7;
            int js = j ^ (row & 7);            // pre-swizzled source chunk (rule #21)
            __builtin_amdgcn_global_load_lds(
                (AS1 const void*)(A + (size_t)(m0 + row) * K + k0 + js * 8),
                (AS3 void*)(&As[sb][c * 8]), 16, 0, 0);
            __builtin_amdgcn_global_load_lds(
                (AS1 const void*)(B + (size_t)(n0 + row) * K + k0 + js * 8),
                (AS3 void*)(&Bs[sb][c * 8]), 16, 0, 0);
        }
    };

    STAGE(0, 0);
    int buf = 0;
    for (int k0 = 0; k0 < K; k0 += 64) {
        __syncthreads();                       // buf ready; buf^1 free
        if (k0 + 64 < K) STAGE(k0 + 64, buf ^ 1);
        #pragma unroll
        for (int kk = 0; kk < 64; kk += 32) {
            const int cx0 = (((kk >> 3) + g) ^ (l15 & 7)) * 8;   // swizzled read chunk
            s16x8 av[2], bv[4];
            #pragma unroll
            for (int mi = 0; mi < 2; ++mi)
                av[mi] = *reinterpret_cast<const s16x8*>(
                    &As[buf][(wm * 32 + mi * 16 + l15) * 64 + cx0]);
            #pragma unroll
            for (int nj = 0; nj < 4; ++nj)
                bv[nj] = *reinterpret_cast<const s16x8*>(
                    &Bs[buf][(wn * 64 + nj * 16 + l15) * 64 + cx0]);
            #pragma unroll
            for (int mi = 0; mi < 2; ++mi)
                #pragma unroll
                for (int nj = 0; nj < 4; ++nj)
                    acc[mi][nj] = __builtin_amdgcn_mfma_f32_16x16x32_bf16(av[mi], bv[nj], acc[mi][nj], 0, 0, 0);
        }
        buf ^= 1;
    }

    #pragma unroll
    for (int nj = 0; nj < 4; ++nj) {
        int n = n0 + wn * 64 + nj * 16 + l15;
        float scale = (n < 1024) ? QSCALE : 1.0f;
        float bvs = bias[n] * scale;
        if (n < 2048) {
            #pragma unroll
            for (int mi = 0; mi < 2; ++mi)
                #pragma unroll
                for (int i = 0; i < 4; ++i) {
                    int m = m0 + wm * 32 + mi * 16 + g * 4 + i;
                    C[(size_t)m * 2048 + n] = f2bf(acc[mi][nj][i] * scale + bvs);
                }
        } else {
            int hd = n - 2048;                       // h*64 + d
            #pragma unroll
            for (int mi = 0; mi < 2; ++mi)
                #pragma unroll
                for (int i = 0; i < 4; ++i) {
                    int m = m0 + wm * 32 + mi * 16 + g * 4 + i;
                    int b = m >> 10, t = m & 1023;
                    vt[((size_t)(b * 16 + (hd >> 6)) * 64 + (hd & 63)) * 1024 + t] =
                        f2bf(acc[mi][nj][i] + bvs);
                }
        }
    }
}

// ---------------- flash attention: per (b, h, 128-row q-block), 8 waves ----------------
// T15 double-pipeline: iteration kt computes QK^T(kt) while finishing
// softmax+PV of kt-1.  K dbuf (2), V triple-buf (3).  Full unroll -> the
// scP=scC hand-off is SSA-renamed (no scratch, rule #20).
__global__ __launch_bounds__(512, 2) void k_flash(const u16* __restrict__ qk,
                                                  const u16* __restrict__ vt,
                                                  float* __restrict__ ml,
                                                  float* __restrict__ cmean) {
    const int id = blockIdx.x + 8 * (blockIdx.y + 16 * blockIdx.z);
    const int x = id & 7, k = id >> 3;          // k in 0..63
    const int gbh = x * 8 + (k >> 3);
    const int qt = k & 7;
    const int b = gbh >> 4, h = gbh & 15;
    const int q0 = qt * 128;
    const int tid = threadIdx.x, lane = tid & 63, w = tid >> 6;  // 8 waves
    const int g = lane >> 4, l15 = lane & 15;
    __shared__ __attribute__((aligned(16))) u16 Ks[2][64 * 64];
    __shared__ __attribute__((aligned(16))) u16 Vt[3][64 * 64];
    __shared__ __attribute__((aligned(16))) u16 Ps[8][16 * 64];

    const size_t rowQ = (size_t)(b * 1024 + q0 + w * 16 + l15) * 2048 + h * 64;
    const s16x8 qa0 = *reinterpret_cast<const s16x8*>(qk + rowQ + g * 8);
    const s16x8 qa1 = *reinterpret_cast<const s16x8*>(qk + rowQ + 32 + g * 8);
    const s16x8 onesv = { (short)0x3F80, (short)0x3F80, (short)0x3F80, (short)0x3F80,
                          (short)0x3F80, (short)0x3F80, (short)0x3F80, (short)0x3F80 };

    // staging: 512 threads cover one 64x64 tile (16B each)
    const int rowA = tid >> 3, jA = tid & 7;
    const int dKA = tid * 8;                    // linear LDS dest (u16 units)
    const u16* kbase0 = qk + (size_t)(b * 1024) * 2048 + 1024 + h * 64;
    const u16* vtb = vt + (size_t)(b * 16 + h) * 65536;
    const u16* gKA = kbase0 + (size_t)rowA * 2048 + ((jA ^ (rowA & 7)) * 8);
    const u16* gVA = vtb + (size_t)rowA * 1024 + ((jA ^ (rowA & 7)) * 8);

    // hoisted LDS read offsets (u16 units)
    int kO[2][4], vO[2], pO[2], pW[4];
    #pragma unroll
    for (int tj = 0; tj < 4; ++tj) {
        int trow = tj * 16 + l15;
        kO[0][tj] = trow * 64 + ((g ^ (trow & 7)) * 8);
        kO[1][tj] = trow * 64 + (((4 + g) ^ (trow & 7)) * 8);
        pW[tj] = l15 * 64 + (((tj * 2 + (g >> 1)) ^ (l15 & 7)) * 8) + (g & 1) * 4;
    }
    pO[0] = l15 * 64 + ((g ^ (l15 & 7)) * 8);
    pO[1] = l15 * 64 + (((4 + g) ^ (l15 & 7)) * 8);
    vO[0] = pO[0];
    vO[1] = pO[1];

    f32x4 ctxa[4];
    #pragma unroll
    for (int nj = 0; nj < 4; ++nj) ctxa[nj] = (f32x4){0.f, 0.f, 0.f, 0.f};
    f32x4 lacc = (f32x4){0.f, 0.f, 0.f, 0.f};

    auto QK = [&](const u16* Kb, f32x4* sc) {
        #pragma unroll
        for (int tj = 0; tj < 4; ++tj) sc[tj] = (f32x4){0.f, 0.f, 0.f, 0.f};
        __builtin_amdgcn_s_setprio(1);
        #pragma unroll
        for (int kki = 0; kki < 2; ++kki) {
            s16x8 qa = kki ? qa1 : qa0;
            #pragma unroll
            for (int tj = 0; tj < 4; ++tj) {
                s16x8 kb = *reinterpret_cast<const s16x8*>(Kb + kO[kki][tj]);
                sc[tj] = __builtin_amdgcn_mfma_f32_16x16x32_bf16(kb, qa, sc[tj], 0, 0, 0);
            }
        }
        __builtin_amdgcn_s_setprio(0);
    };
    auto SMPV = [&](f32x4* sc, const u16* Vb) {
        #pragma unroll
        for (int tj = 0; tj < 4; ++tj)
            #pragma unroll
            for (int i = 0; i < 4; ++i)
                sc[tj][i] = exp2f(sc[tj][i]);
        u16* Pw = &Ps[w][0];
        #pragma unroll
        for (int tj = 0; tj < 4; ++tj) {
            unsigned pk01, pk23;
            asm("v_cvt_pk_bf16_f32 %0, %1, %2" : "=v"(pk01) : "v"(sc[tj][0]), "v"(sc[tj][1]));
            asm("v_cvt_pk_bf16_f32 %0, %1, %2" : "=v"(pk23) : "v"(sc[tj][2]), "v"(sc[tj][3]));
            uint2 pk = { pk01, pk23 };
            *reinterpret_cast<uint2*>(Pw + pW[tj]) = pk;
        }
        __builtin_amdgcn_s_setprio(1);
        #pragma unroll
        for (int kki = 0; kki < 2; ++kki) {
            s16x8 pa = *reinterpret_cast<const s16x8*>(Pw + pO[kki]);
            lacc = __builtin_amdgcn_mfma_f32_16x16x32_bf16(pa, onesv, lacc, 0, 0, 0);
            #pragma unroll
            for (int nj = 0; nj < 4; ++nj) {
                s16x8 vb = *reinterpret_cast<const s16x8*>(Vb + nj * 1024 + vO[kki]);
                ctxa[nj] = __builtin_amdgcn_mfma_f32_16x16x32_bf16(pa, vb, ctxa[nj], 0, 0, 0);
            }
        }
        __builtin_amdgcn_s_setprio(0);
    };

    // prologue: stage kt=0 (K -> Ks[0], V -> Vt[0])
    __builtin_amdgcn_global_load_lds((AS1 const void*)gKA, (AS3 void*)(&Ks[0][dKA]), 16, 0, 0);
    __builtin_amdgcn_global_load_lds((AS1 const void*)gVA, (AS3 void*)(&Vt[0][dKA]), 16, 0, 0);
    gKA += 64 * 2048; gVA += 64;

    // peel kt=0: stage(1), QK(0) -> scP
    f32x4 scP[4];
    __syncthreads();                            // kt=0 data landed
    __builtin_amdgcn_global_load_lds((AS1 const void*)gKA, (AS3 void*)(&Ks[1][dKA]), 16, 0, 0);
    __builtin_amdgcn_global_load_lds((AS1 const void*)gVA, (AS3 void*)(&Vt[1][dKA]), 16, 0, 0);
    gKA += 64 * 2048; gVA += 64;
    QK(&Ks[0][0], scP);

    #pragma unroll
    for (int kt = 1; kt < 16; ++kt) {
        __syncthreads();                        // K(kt)/V(kt) landed; prev reads of overwrite slots done
        if (kt < 15) {
            __builtin_amdgcn_global_load_lds((AS1 const void*)gKA,
                (AS3 void*)(&Ks[(kt + 1) & 1][dKA]), 16, 0, 0);
            __builtin_amdgcn_global_load_lds((AS1 const void*)gVA,
                (AS3 void*)(&Vt[(kt + 1) % 3][dKA]), 16, 0, 0);
            gKA += 64 * 2048; gVA += 64;
        }
        f32x4 scC[4];
        QK(&Ks[kt & 1][0], scC);                // current tile scores
        SMPV(scP, &Vt[(kt - 1) % 3][0]);        // finish previous tile (overlaps QK)
        #pragma unroll
        for (int tj = 0; tj < 4; ++tj) scP[tj] = scC[tj];   // SSA-renamed (full unroll)
    }
    // tail: finish kt=15
    SMPV(scP, &Vt[15 % 3][0]);

    float inv_i[4];
    #pragma unroll
    for (int i = 0; i < 4; ++i) {
        inv_i[i] = 1.0f / lacc[i];
        if (l15 == 0)
            ml[(size_t)(b * 16 + h) * 1024 + q0 + w * 16 + g * 4 + i] = inv_i[i] * 0.0625f;
    }

    #pragma unroll
    for (int nj = 0; nj < 4; ++nj) {
        float s = ctxa[nj][0] * inv_i[0] + ctxa[nj][1] * inv_i[1]
                + ctxa[nj][2] * inv_i[2] + ctxa[nj][3] * inv_i[3];
        s += __shfl_xor(s, 16);
        s += __shfl_xor(s, 32);
        if (g == 0)
            atomicAdd(&cmean[b * 1024 + h * 64 + nj * 16 + l15], s * (1.0f / 1024.0f));
    }
}

// ---------------- attn_weights: mean over heads, 2 s-tiles per block ----------------
__global__ __launch_bounds__(256, 4) void k_attnw(const u16* __restrict__ qk,
                                                  const float* __restrict__ ml,
                                                  float* __restrict__ attnw) {
    const int tt = blockIdx.x, stp = blockIdx.y, b = blockIdx.z;
    const int s0a = stp * 128, t0 = tt * 64;
    const int tid = threadIdx.x, lane = tid & 63, w = tid >> 6;
    const int g = lane >> 4, l15 = lane & 15;
    __shared__ __attribute__((aligned(16))) u16 Ks[2][64 * 64];
    __shared__ float mls[16][128];

    #pragma unroll
    for (int r = 0; r < 8; ++r) {
        int idx = tid + r * 256;
        int hh = idx >> 7, row = idx & 127;
        mls[hh][row] = ml[(size_t)(b * 16 + hh) * 1024 + s0a + row];
    }

    const int cA = tid, cB = tid + 256;
    const int rowA = cA >> 3, jA = cA & 7, rowB = cB >> 3, jB = cB & 7;
    const u16* kbase = qk + (size_t)(b * 1024 + t0) * 2048 + 1024;
    const size_t rowQa = (size_t)(b * 1024 + s0a + w * 16 + l15) * 2048;
    const size_t rowQb = rowQa + (size_t)64 * 2048;

    __builtin_amdgcn_global_load_lds((AS1 const void*)(kbase + (size_t)rowA * 2048 + ((jA ^ (rowA & 7)) * 8)),
                                     (AS3 void*)(&Ks[0][cA * 8]), 16, 0, 0);
    __builtin_amdgcn_global_load_lds((AS1 const void*)(kbase + (size_t)rowB * 2048 + ((jB ^ (rowB & 7)) * 8)),
                                     (AS3 void*)(&Ks[0][cB * 8]), 16, 0, 0);
    s16x8 qcA0 = *reinterpret_cast<const s16x8*>(qk + rowQa + g * 8);
    s16x8 qcA1 = *reinterpret_cast<const s16x8*>(qk + rowQa + 32 + g * 8);
    s16x8 qcB0 = *reinterpret_cast<const s16x8*>(qk + rowQb + g * 8);
    s16x8 qcB1 = *reinterpret_cast<const s16x8*>(qk + rowQb + 32 + g * 8);

    f32x4 accA[4], accB[4];
    #pragma unroll
    for (int tj = 0; tj < 4; ++tj) {
        accA[tj] = (f32x4){0.f, 0.f, 0.f, 0.f};
        accB[tj] = (f32x4){0.f, 0.f, 0.f, 0.f};
    }

    int buf = 0;
    for (int h = 0; h < 16; ++h) {
        __syncthreads();
        s16x8 qnA0, qnA1, qnB0, qnB1;
        if (h < 15) {
            const u16* kb2 = kbase + (h + 1) * 64;
            __builtin_amdgcn_global_load_lds((AS1 const void*)(kb2 + (size_t)rowA * 2048 + ((jA ^ (rowA & 7)) * 8)),
                                             (AS3 void*)(&Ks[buf ^ 1][cA * 8]), 16, 0, 0);
            __builtin_amdgcn_global_load_lds((AS1 const void*)(kb2 + (size_t)rowB * 2048 + ((jB ^ (rowB & 7)) * 8)),
                                             (AS3 void*)(&Ks[buf ^ 1][cB * 8]), 16, 0, 0);
            qnA0 = *reinterpret_cast<const s16x8*>(qk + rowQa + (h + 1) * 64 + g * 8);
            qnA1 = *reinterpret_cast<const s16x8*>(qk + rowQa + (h + 1) * 64 + 32 + g * 8);
            qnB0 = *reinterpret_cast<const s16x8*>(qk + rowQb + (h + 1) * 64 + g * 8);
            qnB1 = *reinterpret_cast<const s16x8*>(qk + rowQb + (h + 1) * 64 + 32 + g * 8);
        }

        f32x4 scA[4], scB[4];
        #pragma unroll
        for (int tj = 0; tj < 4; ++tj) {
            scA[tj] = (f32x4){0.f, 0.f, 0.f, 0.f};
            scB[tj] = (f32x4){0.f, 0.f, 0.f, 0.f};
        }
        #pragma unroll
        for (int kk = 0; kk < 64; kk += 32) {
            s16x8 qaA = kk ? qcA1 : qcA0;
            s16x8 qaB = kk ? qcB1 : qcB0;
            #pragma unroll
            for (int tj = 0; tj < 4; ++tj) {
                int trow = tj * 16 + l15;
                s16x8 kb = *reinterpret_cast<const s16x8*>(
                    &Ks[buf][trow * 64 + ((((kk >> 3) + g) ^ (trow & 7)) * 8)]);
                scA[tj] = __builtin_amdgcn_mfma_f32_16x16x32_bf16(qaA, kb, scA[tj], 0, 0, 0);
                scB[tj] = __builtin_amdgcn_mfma_f32_16x16x32_bf16(qaB, kb, scB[tj], 0, 0, 0);
            }
        }
        #pragma unroll
        for (int i = 0; i < 4; ++i) {
            int row = w * 16 + g * 4 + i;
            float Ma = mls[h][row];
            float Mb = mls[h][64 + row];
            #pragma unroll
            for (int tj = 0; tj < 4; ++tj) {
                accA[tj][i] += exp2f(scA[tj][i]) * Ma;
                accB[tj][i] += exp2f(scB[tj][i]) * Mb;
            }
        }
        qcA0 = qnA0; qcA1 = qnA1; qcB0 = qnB0; qcB1 = qnB1;
        buf ^= 1;
    }

    #pragma unroll
    for (int i = 0; i < 4; ++i) {
        int rowa = s0a + w * 16 + g * 4 + i;
        #pragma unroll
        for (int tj = 0; tj < 4; ++tj) {
            attnw[(size_t)(b * 1024 + rowa) * 1024 + t0 + tj * 16 + l15] = accA[tj][i];
            attnw[(size_t)(b * 1024 + rowa + 64) * 1024 + t0 + tj * 16 + l15] = accB[tj][i];
        }
    }
}

// ---------------- out-proj on the mean: 256 blk, one wave per output row ----------------
// Lane ls of wave (e) handles k-floats [ls*16, ls*16+16); full-wave shfl reduce.
__global__ __launch_bounds__(256) void k_outproj(const float* __restrict__ cmean,
                                                 const float* __restrict__ wout,
                                                 const float* __restrict__ bias,
                                                 float* __restrict__ out) {
    __shared__ float cs[4096];
    #pragma unroll
    for (int r = 0; r < 16; ++r) {
        int idx = threadIdx.x + r * 256;
        cs[idx] = cmean[idx];
    }
    __syncthreads();
    int G = blockIdx.x * 256 + threadIdx.x;   // 0..65535
    int e = G >> 6, ls = G & 63;              // wave-uniform e (blk*4 + wave)
    const float4* wr = reinterpret_cast<const float4*>(wout) + (size_t)e * 256 + ls * 4;
    const float4* c0 = reinterpret_cast<const float4*>(&cs[0]) + ls * 4;
    const float4* c1 = reinterpret_cast<const float4*>(&cs[1024]) + ls * 4;
    const float4* c2 = reinterpret_cast<const float4*>(&cs[2048]) + ls * 4;
    const float4* c3 = reinterpret_cast<const float4*>(&cs[3072]) + ls * 4;
    float s0 = 0.f, s1 = 0.f, s2 = 0.f, s3 = 0.f;
    #pragma unroll
    for (int k = 0; k < 4; ++k) {
        float4 wv = wr[k];
        float4 a = c0[k], b = c1[k], c = c2[k], d = c3[k];
        s0 += a.x * wv.x + a.y * wv.y + a.z * wv.z + a.w * wv.w;
        s1 += b.x * wv.x + b.y * wv.y + b.z * wv.z + b.w * wv.w;
        s2 += c.x * wv.x + c.y * wv.y + c.z * wv.z + c.w * wv.w;
        s3 += d.x * wv.x + d.y * wv.y + d.z * wv.z + d.w * wv.w;
    }
    #pragma unroll
    for (int off = 1; off < 64; off <<= 1) {
        s0 += __shfl_xor(s0, off);
        s1 += __shfl_xor(s1, off);
        s2 += __shfl_xor(s2, off);
        s3 += __shfl_xor(s3, off);
    }
    if (ls == 0) {
        float bv = bias[e];
        out[e]        = s0 + bv;
        out[1024 + e] = s1 + bv;
        out[2048 + e] = s2 + bv;
        out[3072 + e] = s3 + bv;
    }
}

// ---------------- launch ----------------
extern "C" void kernel_launch(void* const* d_in, const int* in_sizes, int n_in,
                              void* d_out, int out_size, void* d_ws, size_t ws_size,
                              hipStream_t stream) {
    const float* lstm = (const float*)d_in[0];   // [4,1024,1024]
    const float* wqkv = (const float*)d_in[1];   // [3072,1024]
    const float* bqkv = (const float*)d_in[2];   // [3072]
    const float* wout = (const float*)d_in[3];   // [1024,1024]
    const float* bout = (const float*)d_in[4];   // [1024]
    float* out = (float*)d_out;                  // [4096 ctxvec | 4*1024*1024 attn]

    char* ws = (char*)d_ws;
    u16*   Xbf   = (u16*)(ws);                          // 8 MiB
    u16*   Wqkvb = (u16*)(ws + 8u  * 1024 * 1024);      // 6 MiB
    u16*   qkbuf = (u16*)(ws + 16u * 1024 * 1024);      // 16 MiB  [4096][2048]
    u16*   vtg   = (u16*)(ws + 32u * 1024 * 1024);      // 8 MiB   [64][64][1024]
    float* ml    = (float*)(ws + 40u * 1024 * 1024);    // 256 KiB (invl/16)
    float* cmean = (float*)(ws + 41u * 1024 * 1024);    // 16 KiB  [4][1024]

    k_prep<<<7168, 256, 0, stream>>>(lstm, wqkv, Xbf, Wqkvb, cmean);

    k_gemm_bt<<<dim3(24, 32), 512, 0, stream>>>(Xbf, Wqkvb, bqkv, qkbuf, vtg);
    k_flash<<<dim3(8, 16, 4), 512, 0, stream>>>(qkbuf, vtg, ml, cmean);
    k_attnw<<<dim3(16, 8, 4), 256, 0, stream>>>(qkbuf, ml, out + 4096);
    k_outproj<<<256, 256, 0, stream>>>(cmean, wout, bout, out);
}